// Round 25
// baseline (348.752 us; speedup 1.0000x reference)
//
#include <hip/hip_runtime.h>
#include <hip/hip_bf16.h>

typedef __attribute__((ext_vector_type(8))) short short8;
typedef __attribute__((ext_vector_type(4))) float f32x4;
using bf16 = __hip_bfloat16;

__device__ __forceinline__ void gload16(const void* g, void* l) {
  __builtin_amdgcn_global_load_lds(
      (const __attribute__((address_space(1))) void*)g,
      (__attribute__((address_space(3))) void*)l, 16, 0, 0);
}

__device__ __forceinline__ short f2bf(float f) {
  bf16 h = __float2bfloat16(f);
  short s;
  __builtin_memcpy(&s, &h, 2);
  return s;
}

__device__ __forceinline__ float bf2f(unsigned short u) {
  unsigned int x = ((unsigned int)u) << 16;
  float f;
  __builtin_memcpy(&f, &x, 4);
  return f;
}

// ------------- batched weight transpose fp32[1024][1024] -> bf16[C][R] ------
__global__ __launch_bounds__(256)
void wtr8(const float* w0, const float* w1, const float* w2, const float* w3,
          const float* w4, const float* w5, const float* w6, const float* w7,
          bf16* __restrict__ Wout) {
  __shared__ float tile[32][33];
  const float* w;
  switch (blockIdx.z) {
    case 0: w = w0; break; case 1: w = w1; break;
    case 2: w = w2; break; case 3: w = w3; break;
    case 4: w = w4; break; case 5: w = w5; break;
    case 6: w = w6; break; default: w = w7; break;
  }
  bf16* wt = Wout + (size_t)blockIdx.z * 1024 * 1024;
  const int tx = threadIdx.x & 31, ty = threadIdx.x >> 5;
  const int c0 = blockIdx.x * 32, r0 = blockIdx.y * 32;
#pragma unroll
  for (int i = 0; i < 4; ++i)
    tile[ty * 4 + i][tx] = w[(size_t)(r0 + ty * 4 + i) * 1024 + c0 + tx];
  __syncthreads();
#pragma unroll
  for (int i = 0; i < 4; ++i) {
    const int cc = ty * 4 + i;
    wt[(size_t)(c0 + cc) * 1024 + r0 + tx] = __float2bfloat16(tile[tx][cc]);
  }
}

// ---------------- weight transpose fp32[R][C] -> bf16[C][R] ----------------
__global__ __launch_bounds__(256)
void wtr(const float* __restrict__ w, bf16* __restrict__ wt, int R, int C) {
  __shared__ float tile[32][33];
  const int tx = threadIdx.x & 31, ty = threadIdx.x >> 5;
  const int c0 = blockIdx.x * 32, r0 = blockIdx.y * 32;
#pragma unroll
  for (int i = 0; i < 4; ++i)
    tile[ty * 4 + i][tx] = w[(size_t)(r0 + ty * 4 + i) * C + c0 + tx];
  __syncthreads();
#pragma unroll
  for (int i = 0; i < 4; ++i) {
    const int cc = ty * 4 + i;
    wt[(size_t)(c0 + cc) * R + r0 + tx] = __float2bfloat16(tile[tx][cc]);
  }
}

// ---------------- LayerNorm fp32 row(1024) -> bf16 ----------------
__global__ __launch_bounds__(256)
void ln_k(const float* __restrict__ x, const float* __restrict__ g,
          const float* __restrict__ b, bf16* __restrict__ y) {
  const int row = blockIdx.x, t = threadIdx.x;
  const int wv = t >> 6, l = t & 63;
  const float4 v = reinterpret_cast<const float4*>(x + (size_t)row * 1024)[t];
  float s = v.x + v.y + v.z + v.w;
  float s2 = v.x * v.x + v.y * v.y + v.z * v.z + v.w * v.w;
#pragma unroll
  for (int m = 1; m < 64; m <<= 1) {
    s += __shfl_xor(s, m, 64);
    s2 += __shfl_xor(s2, m, 64);
  }
  __shared__ float ps[4], ps2[4];
  if (l == 0) { ps[wv] = s; ps2[wv] = s2; }
  __syncthreads();
  s = ps[0] + ps[1] + ps[2] + ps[3];
  s2 = ps2[0] + ps2[1] + ps2[2] + ps2[3];
  const float mean = s * (1.f / 1024.f);
  const float var = s2 * (1.f / 1024.f) - mean * mean;
  const float rs = rsqrtf(var + 1e-5f);
  const float4 gg = reinterpret_cast<const float4*>(g)[t];
  const float4 bb = reinterpret_cast<const float4*>(b)[t];
  ushort4 o;
  o.x = (unsigned short)f2bf((v.x - mean) * rs * gg.x + bb.x);
  o.y = (unsigned short)f2bf((v.y - mean) * rs * gg.y + bb.y);
  o.z = (unsigned short)f2bf((v.z - mean) * rs * gg.z + bb.z);
  o.w = (unsigned short)f2bf((v.w - mean) * rs * gg.w + bb.w);
  reinterpret_cast<ushort4*>(y + (size_t)row * 1024)[t] = o;
}

// ---- combine of 4 bf16 split-K partials ----
// MODE 0: f32 out = sum + res;  MODE 1: bf16 out = sum;
// MODE 2: f32 out = sum + res + bias (bias per col, N=1024)
template <int MODE>
__global__ __launch_bounds__(256)
void comb4(const ushort4* __restrict__ p0, const ushort4* __restrict__ p1,
           const ushort4* __restrict__ p2, const ushort4* __restrict__ p3,
           const float4* __restrict__ res, const float4* __restrict__ bias,
           void* __restrict__ outv) {
  const size_t i = (size_t)blockIdx.x * 256 + threadIdx.x;
  const ushort4 a = p0[i], b = p1[i], c = p2[i], d = p3[i];
  float sx = (bf2f(a.x) + bf2f(b.x)) + (bf2f(c.x) + bf2f(d.x));
  float sy = (bf2f(a.y) + bf2f(b.y)) + (bf2f(c.y) + bf2f(d.y));
  float sz = (bf2f(a.z) + bf2f(b.z)) + (bf2f(c.z) + bf2f(d.z));
  float sw = (bf2f(a.w) + bf2f(b.w)) + (bf2f(c.w) + bf2f(d.w));
  if constexpr (MODE == 1) {
    ushort4 o;
    o.x = (unsigned short)f2bf(sx);
    o.y = (unsigned short)f2bf(sy);
    o.z = (unsigned short)f2bf(sz);
    o.w = (unsigned short)f2bf(sw);
    ((ushort4*)outv)[i] = o;
  } else {
    const float4 r = res[i];
    float4 o;
    if constexpr (MODE == 2) {
      const float4 g = bias[i & 255];
      o.x = sx + r.x + g.x; o.y = sy + r.y + g.y;
      o.z = sz + r.z + g.z; o.w = sw + r.w + g.w;
    } else {
      o.x = sx + r.x; o.y = sy + r.y; o.z = sz + r.z; o.w = sw + r.w;
    }
    ((float4*)outv)[i] = o;
  }
}

// ---- GEMM 256x256 tile, 8 waves (2Mx4N), dual-barrier counted vmcnt(8) ----
// LDS 128 KB (2-stage). Per wave: 128x64 output, 64 MFMA per K-step.
// lda = leading dim of A/BT rows (exceeds K for split-K slices).
// EPI: 2 = bf16 relu(acc+bias) to outp ld N (FFN-up);
//      5 = split-K partial: slice z reads cols [z*K,(z+1)*K), writes BF16
//          partial to (bf16*)outp + z*M*N
template <int EPI>
__global__ __launch_bounds__(512, 1)
void gemm256(const bf16* __restrict__ A, const bf16* __restrict__ BT,
             const float* __restrict__ bias, void* __restrict__ outp,
             int M, int N, int K, int lda) {
  __shared__ alignas(16) short al[2][256 * 64];
  __shared__ alignas(16) short bl[2][256 * 64];
  const int t = threadIdx.x;
  const int gx = N >> 8;
  const int nwg = gridDim.x * gridDim.y;
  int id = blockIdx.y * gridDim.x + blockIdx.x;
  id = (id & 7) * (nwg >> 3) + (id >> 3);  // XCD-chunked (nwg%8==0)
  const int bx = id % gx, by = id / gx;
  const int m0 = by * 256, n0 = bx * 256;
  const int wid = t >> 6, l = t & 63, lr = l & 15, lk = l >> 4;
  const int wm = wid >> 2, wn = wid & 3;
  const int tr = t >> 3, tc = (t & 7) * 8;
  const int tcs = (((t & 7) ^ (tr & 7)) * 8);
  const int cro0 = ((lk ^ (lr & 7)) * 8);
  const int cro1 = (((4 + lk) ^ (lr & 7)) * 8);

  const bf16* Ab = (EPI == 5) ? A + (size_t)blockIdx.z * K : A;
  const bf16* BTb = (EPI == 5) ? BT + (size_t)blockIdx.z * K : BT;

  f32x4 acc[8][4];
#pragma unroll
  for (int i = 0; i < 8; ++i)
#pragma unroll
    for (int j = 0; j < 4; ++j) acc[i][j] = (f32x4)0.f;

#define STAGE2(buf, k0)                                                       \
  do {                                                                        \
    _Pragma("unroll") for (int it = 0; it < 4; ++it) {                        \
      const int row = it * 64 + tr;                                           \
      gload16(Ab + (size_t)(m0 + row) * lda + (k0) + tcs,                     \
              (char*)&al[buf][row * 64 + tc]);                                \
    }                                                                         \
    _Pragma("unroll") for (int it = 0; it < 4; ++it) {                        \
      const int row = it * 64 + tr;                                           \
      gload16(BTb + (size_t)(n0 + row) * lda + (k0) + tcs,                    \
              (char*)&bl[buf][row * 64 + tc]);                                \
    }                                                                         \
  } while (0)

#define COMPUTE2(cur)                                                         \
  do {                                                                        \
    _Pragma("unroll") for (int ks = 0; ks < 2; ++ks) {                        \
      const int cro = ks ? cro1 : cro0;                                       \
      short8 af[8], bfv[4];                                                   \
      _Pragma("unroll") for (int m = 0; m < 8; ++m) af[m] =                   \
          *reinterpret_cast<const short8*>(                                   \
              &al[cur][(wm * 128 + m * 16 + lr) * 64 + cro]);                 \
      _Pragma("unroll") for (int n = 0; n < 4; ++n) bfv[n] =                  \
          *reinterpret_cast<const short8*>(                                   \
              &bl[cur][(wn * 64 + n * 16 + lr) * 64 + cro]);                  \
      _Pragma("unroll") for (int m = 0; m < 8; ++m)                           \
          _Pragma("unroll") for (int n = 0; n < 4; ++n) acc[m][n] =           \
              __builtin_amdgcn_mfma_f32_16x16x32_bf16(af[m], bfv[n],          \
                                                      acc[m][n], 0, 0, 0);    \
    }                                                                         \
  } while (0)

  const int nt = K >> 6;
  STAGE2(0, 0);
  STAGE2(1, 64);
  for (int tk = 0; tk < nt; ++tk) {
    const int cur = tk & 1;
    if (tk < nt - 1)
      asm volatile("s_waitcnt vmcnt(8)" ::: "memory");
    else
      asm volatile("s_waitcnt vmcnt(0)" ::: "memory");
    __builtin_amdgcn_s_barrier();
    COMPUTE2(cur);
    if (tk + 2 < nt) {
      asm volatile("s_waitcnt lgkmcnt(0)" ::: "memory");
      __builtin_amdgcn_s_barrier();
      STAGE2(cur, (tk + 2) << 6);
    }
  }
#undef STAGE2
#undef COMPUTE2

  const int r0 = m0 + wm * 128, c0 = n0 + wn * 64;
  if constexpr (EPI == 2) {
#pragma unroll
    for (int m = 0; m < 8; ++m)
#pragma unroll
      for (int n = 0; n < 4; ++n) {
        const int col = c0 + n * 16 + lr;
        const float bcol = bias[col];
#pragma unroll
        for (int r = 0; r < 4; ++r) {
          const int row = r0 + m * 16 + lk * 4 + r;
          const float v = acc[m][n][r] + bcol;
          ((bf16*)outp)[(size_t)row * N + col] =
              __float2bfloat16(fmaxf(v, 0.f));
        }
      }
  } else {
    bf16* po = (bf16*)outp + (size_t)blockIdx.z * M * N;
#pragma unroll
    for (int m = 0; m < 8; ++m)
#pragma unroll
      for (int n = 0; n < 4; ++n) {
        const int col = c0 + n * 16 + lr;
#pragma unroll
        for (int r = 0; r < 4; ++r) {
          const int row = r0 + m * 16 + lk * 4 + r;
          po[(size_t)row * N + col] = __float2bfloat16(acc[m][n][r]);
        }
      }
  }
}

// ---- Merged QKV + cross-KV on the 256x256 structure (320 blocks) ----------
__global__ __launch_bounds__(512, 1)
void gemm256_dual(const bf16* __restrict__ A0, const bf16* __restrict__ BT0,
                  bf16* __restrict__ out0, bf16* __restrict__ vt0,
                  const bf16* __restrict__ A1, const bf16* __restrict__ BT1,
                  bf16* __restrict__ out1, bf16* __restrict__ vt1) {
  __shared__ alignas(16) short al[2][256 * 64];
  __shared__ alignas(16) short bl[2][256 * 64];
  const int t = threadIdx.x;
  const int raw = blockIdx.x;
  const int id = (raw & 7) * 40 + (raw >> 3);  // 320 = 8*40, bijective
  const bf16 *A, *BT;
  bf16 *outp, *vtp;
  int nv0, gx, pid;
  if (id < 192) {
    A = A0; BT = BT0; outp = out0; vtp = vt0; nv0 = 2048; gx = 12; pid = id;
  } else {
    A = A1; BT = BT1; outp = out1; vtp = vt1; nv0 = 1024; gx = 8;
    pid = id - 192;
  }
  const int K = 1024;
  const int bx = pid % gx, by = pid / gx;
  const int m0 = by * 256, n0 = bx * 256;
  const int wid = t >> 6, l = t & 63, lr = l & 15, lk = l >> 4;
  const int wm = wid >> 2, wn = wid & 3;
  const int tr = t >> 3, tc = (t & 7) * 8;
  const int tcs = (((t & 7) ^ (tr & 7)) * 8);
  const int cro0 = ((lk ^ (lr & 7)) * 8);
  const int cro1 = (((4 + lk) ^ (lr & 7)) * 8);

  f32x4 acc[8][4];
#pragma unroll
  for (int i = 0; i < 8; ++i)
#pragma unroll
    for (int j = 0; j < 4; ++j) acc[i][j] = (f32x4)0.f;

#define STAGE2(buf, k0)                                                       \
  do {                                                                        \
    _Pragma("unroll") for (int it = 0; it < 4; ++it) {                        \
      const int row = it * 64 + tr;                                           \
      gload16(A + (size_t)(m0 + row) * K + (k0) + tcs,                        \
              (char*)&al[buf][row * 64 + tc]);                                \
    }                                                                         \
    _Pragma("unroll") for (int it = 0; it < 4; ++it) {                        \
      const int row = it * 64 + tr;                                           \
      gload16(BT + (size_t)(n0 + row) * K + (k0) + tcs,                       \
              (char*)&bl[buf][row * 64 + tc]);                                \
    }                                                                         \
  } while (0)

#define COMPUTE2(cur)                                                         \
  do {                                                                        \
    _Pragma("unroll") for (int ks = 0; ks < 2; ++ks) {                        \
      const int cro = ks ? cro1 : cro0;                                       \
      short8 af[8], bfv[4];                                                   \
      _Pragma("unroll") for (int m = 0; m < 8; ++m) af[m] =                   \
          *reinterpret_cast<const short8*>(                                   \
              &al[cur][(wm * 128 + m * 16 + lr) * 64 + cro]);                 \
      _Pragma("unroll") for (int n = 0; n < 4; ++n) bfv[n] =                  \
          *reinterpret_cast<const short8*>(                                   \
              &bl[cur][(wn * 64 + n * 16 + lr) * 64 + cro]);                  \
      _Pragma("unroll") for (int m = 0; m < 8; ++m)                           \
          _Pragma("unroll") for (int n = 0; n < 4; ++n) acc[m][n] =           \
              __builtin_amdgcn_mfma_f32_16x16x32_bf16(af[m], bfv[n],          \
                                                      acc[m][n], 0, 0, 0);    \
    }                                                                         \
  } while (0)

  const int nt = K >> 6;
  STAGE2(0, 0);
  STAGE2(1, 64);
  for (int tk = 0; tk < nt; ++tk) {
    const int cur = tk & 1;
    if (tk < nt - 1)
      asm volatile("s_waitcnt vmcnt(8)" ::: "memory");
    else
      asm volatile("s_waitcnt vmcnt(0)" ::: "memory");
    __builtin_amdgcn_s_barrier();
    COMPUTE2(cur);
    if (tk + 2 < nt) {
      asm volatile("s_waitcnt lgkmcnt(0)" ::: "memory");
      __builtin_amdgcn_s_barrier();
      STAGE2(cur, (tk + 2) << 6);
    }
  }
#undef STAGE2
#undef COMPUTE2

  const int r0 = m0 + wm * 128, c0 = n0 + wn * 64;
#pragma unroll
  for (int m = 0; m < 8; ++m) {
    const int rowb = r0 + m * 16 + lk * 4;
    const int bb = rowb >> 10, s0 = rowb & 1023;
#pragma unroll
    for (int n = 0; n < 4; ++n) {
      const int col = c0 + n * 16 + lr;
      if (col < nv0) {
#pragma unroll
        for (int r = 0; r < 4; ++r)
          outp[(size_t)(rowb + r) * nv0 + col] =
              __float2bfloat16(acc[m][n][r]);
      } else {
        ushort4 u;
        u.x = (unsigned short)f2bf(acc[m][n][0]);
        u.y = (unsigned short)f2bf(acc[m][n][1]);
        u.z = (unsigned short)f2bf(acc[m][n][2]);
        u.w = (unsigned short)f2bf(acc[m][n][3]);
        const size_t vidx = ((size_t)bb * 1024 + (col - nv0)) * 1024 + s0;
        *reinterpret_cast<ushort4*>(vtp + vidx) = u;
      }
    }
  }
}

// ---------------- Flash attention v8: LDS-staged K/V, 3-stage pipeline ------
template <bool CAUSAL>
__global__ __launch_bounds__(256, 2)
void flash8(const bf16* __restrict__ Qb, int ldq,
            const bf16* __restrict__ Kb, int ldk,
            const bf16* __restrict__ VTb, bf16* __restrict__ Ob) {
  __shared__ alignas(16) short kl[3][64 * 64];
  __shared__ alignas(16) short vl[3][64 * 64];
  __shared__ alignas(16) short pl[4][32 * 72];
  const int t = threadIdx.x, wv = t >> 6, l = t & 63, lr = l & 15, lk = l >> 4;
  const int raw = blockIdx.y * 8 + blockIdx.x;
  const int id = (raw & 7) * 64 + (raw >> 3);
  const int qb = id & 7, bh = id >> 3;
  const int b = bh >> 4, h = bh & 15;
  const size_t rowbase = (size_t)b * 1024;
  const int q0 = qb * 128 + wv * 32;
  const bf16* Vbase = VTb + (rowbase + h * 64) * 1024;

  const int tr = t >> 3;
  const int tcd = (t & 7) * 8;
  const int tcs = (((t & 7) ^ (tr & 7)) * 8);
  const int cro0 = ((lk ^ (lr & 7)) * 8);
  const int cro1 = (((4 + lk) ^ (lr & 7)) * 8);

  short8 qf[2][2];
#pragma unroll
  for (int m = 0; m < 2; ++m)
#pragma unroll
    for (int ks = 0; ks < 2; ++ks)
      qf[m][ks] = *reinterpret_cast<const short8*>(
          Qb + (rowbase + q0 + m * 16 + lr) * ldq + h * 64 + ks * 32 + lk * 8);

  short8 ones;
#pragma unroll
  for (int j = 0; j < 8; ++j) ones[j] = (short)0x3F80;  // bf16 1.0

  f32x4 accO[2][4];
  f32x4 accL[2];
#pragma unroll
  for (int m = 0; m < 2; ++m) {
#pragma unroll
    for (int n = 0; n < 4; ++n) accO[m][n] = (f32x4)0.f;
    accL[m] = (f32x4)0.f;
  }

  const int ntb = CAUSAL ? (qb * 2 + 2) : 16;
  const int myLast = q0 >> 6;

#define FSTAGE(buf, kv0)                                                      \
  do {                                                                        \
    _Pragma("unroll") for (int it = 0; it < 2; ++it) {                        \
      const int row = it * 32 + tr;                                           \
      gload16(Kb + (rowbase + (kv0) + row) * ldk + h * 64 + tcs,              \
              (char*)&kl[buf][row * 64 + tcd]);                               \
    }                                                                         \
    _Pragma("unroll") for (int it = 0; it < 2; ++it) {                        \
      const int row = it * 32 + tr;                                           \
      gload16(Vbase + (size_t)row * 1024 + (kv0) + tcs,                       \
              (char*)&vl[buf][row * 64 + tcd]);                               \
    }                                                                         \
  } while (0)

  FSTAGE(0, 0);
  FSTAGE(1, 64);
  int cur = 0;
  for (int tk = 0; tk < ntb; ++tk) {
    if (tk < ntb - 1)
      asm volatile("s_waitcnt vmcnt(4)" ::: "memory");
    else
      asm volatile("s_waitcnt vmcnt(0)" ::: "memory");
    __builtin_amdgcn_s_barrier();
    if (tk + 2 < ntb) {
      int stg = cur + 2;
      if (stg >= 3) stg -= 3;
      FSTAGE(stg, (tk + 2) << 6);
    }
    if (!CAUSAL || tk <= myLast) {
      const int kv0 = tk * 64;
      const bool needmask = CAUSAL && (tk == myLast);
      f32x4 sa[2][4];
#pragma unroll
      for (int m = 0; m < 2; ++m)
#pragma unroll
        for (int n = 0; n < 4; ++n) sa[m][n] = (f32x4)0.f;
#pragma unroll
      for (int ks = 0; ks < 2; ++ks) {
        const int cro = ks ? cro1 : cro0;
        short8 kf[4];
#pragma unroll
        for (int n = 0; n < 4; ++n)
          kf[n] = *reinterpret_cast<const short8*>(
              &kl[cur][(n * 16 + lr) * 64 + cro]);
        __builtin_amdgcn_s_setprio(1);
#pragma unroll
        for (int m = 0; m < 2; ++m)
#pragma unroll
          for (int n = 0; n < 4; ++n)
            sa[m][n] = __builtin_amdgcn_mfma_f32_16x16x32_bf16(
                qf[m][ks], kf[n], sa[m][n], 0, 0, 0);
        __builtin_amdgcn_s_setprio(0);
      }
#pragma unroll
      for (int m = 0; m < 2; ++m) {
#pragma unroll
        for (int r = 0; r < 4; ++r) {
          const int row = q0 + m * 16 + lk * 4 + r;
          float s0 = sa[m][0][r] * 0.125f, s1 = sa[m][1][r] * 0.125f;
          float s2 = sa[m][2][r] * 0.125f, s3 = sa[m][3][r] * 0.125f;
          if (needmask) {
            if (kv0 + 0 + lr > row) s0 = -1e30f;
            if (kv0 + 16 + lr > row) s1 = -1e30f;
            if (kv0 + 32 + lr > row) s2 = -1e30f;
            if (kv0 + 48 + lr > row) s3 = -1e30f;
          }
          const float p0 = __expf(s0), p1 = __expf(s1);
          const float p2 = __expf(s2), p3 = __expf(s3);
          const int prow = m * 16 + lk * 4 + r;
          pl[wv][prow * 72 + lr + 0] = f2bf(p0);
          pl[wv][prow * 72 + lr + 16] = f2bf(p1);
          pl[wv][prow * 72 + lr + 32] = f2bf(p2);
          pl[wv][prow * 72 + lr + 48] = f2bf(p3);
        }
      }
#pragma unroll
      for (int ks = 0; ks < 2; ++ks) {
        const int cro = ks ? cro1 : cro0;
        short8 pf[2], vf[4];
#pragma unroll
        for (int m = 0; m < 2; ++m)
          pf[m] = *reinterpret_cast<const short8*>(
              &pl[wv][(m * 16 + lr) * 72 + ks * 32 + lk * 8]);
#pragma unroll
        for (int n = 0; n < 4; ++n)
          vf[n] = *reinterpret_cast<const short8*>(
              &vl[cur][(n * 16 + lr) * 64 + cro]);
        __builtin_amdgcn_s_setprio(1);
#pragma unroll
        for (int m = 0; m < 2; ++m) {
#pragma unroll
          for (int n = 0; n < 4; ++n)
            accO[m][n] = __builtin_amdgcn_mfma_f32_16x16x32_bf16(
                pf[m], vf[n], accO[m][n], 0, 0, 0);
          accL[m] = __builtin_amdgcn_mfma_f32_16x16x32_bf16(
              pf[m], ones, accL[m], 0, 0, 0);
        }
        __builtin_amdgcn_s_setprio(0);
      }
    }
    cur = (cur + 1 == 3) ? 0 : cur + 1;
  }
#undef FSTAGE

#pragma unroll
  for (int m = 0; m < 2; ++m)
#pragma unroll
    for (int n = 0; n < 4; ++n)
#pragma unroll
      for (int r = 0; r < 4; ++r) {
        const int row = q0 + m * 16 + lk * 4 + r;
        const int col = n * 16 + lr;
        const float o = accO[m][n][r] / accL[m][r];
        Ob[(rowbase + row) * 1024 + h * 64 + col] = __float2bfloat16(o);
      }
}

// ---------------- launch ----------------
extern "C" void kernel_launch(void* const* d_in, const int* in_sizes, int n_in,
                              void* d_out, int out_size, void* d_ws,
                              size_t ws_size, hipStream_t stream) {
  const float* x = (const float*)d_in[0];
  const float* kv_in = (const float*)d_in[1];
  const float* sa_wq = (const float*)d_in[4];
  const float* sa_wk = (const float*)d_in[5];
  const float* sa_wv = (const float*)d_in[6];
  const float* sa_wo = (const float*)d_in[7];
  const float* ca_wq = (const float*)d_in[8];
  const float* ca_wk = (const float*)d_in[9];
  const float* ca_wv = (const float*)d_in[10];
  const float* ca_wo = (const float*)d_in[11];
  const float* fc_w1 = (const float*)d_in[12];
  const float* fc_b1 = (const float*)d_in[13];
  const float* fc_w2 = (const float*)d_in[14];
  const float* fc_b2 = (const float*)d_in[15];
  const float* ln1_g = (const float*)d_in[16];
  const float* ln1_b = (const float*)d_in[17];
  const float* ln2_g = (const float*)d_in[18];
  const float* ln2_b = (const float*)d_in[19];
  const float* ln3_g = (const float*)d_in[20];
  const float* ln3_b = (const float*)d_in[21];

  char* ws = (char*)d_ws;
  const size_t MB = 1024 * 1024;
  bf16* W = (bf16*)ws;                    // 16M elems = 32 MB
  bf16* w1T = W + 8 * MB;
  bf16* w2T = W + 12 * MB;
  float* z = (float*)(ws + 32 * MB);      // 16 MB
  bf16* t0 = (bf16*)(ws + 48 * MB);       // 8 MB
  bf16* qkvb = (bf16*)(ws + 56 * MB);     // [4096][2048] Q|K, 16 MB
  bf16* vts = (bf16*)(ws + 72 * MB);      // self V^T [4096][1024], 8 MB
  bf16* kb = (bf16*)(ws + 80 * MB);       // cross K [4096][1024], 8 MB
  bf16* vtc = (bf16*)(ws + 88 * MB);      // cross V^T [4096][1024], 8 MB
  bf16* qb = (bf16*)(ws + 96 * MB);       // 8 MB
  bf16* ctx = (bf16*)(ws + 104 * MB);     // 8 MB
  bf16* kvln = (bf16*)(ws + 112 * MB);    // 8 MB
  bf16* hb = (bf16*)(ws + 120 * MB);      // [4096][4096] 32 MB
  // bf16 split-K partial regions (4 x 8 MB each):
  bf16* partsO = (bf16*)(ws + 120 * MB);  // over hb (dead until FFN-up)
  bf16* partsb = (bf16*)(ws + 56 * MB);   // over qkvb..kb (dead after attn)
  const size_t PSL = (size_t)4096 * 1024; // partial slice elems

  const dim3 B256(256);
  wtr8<<<dim3(32, 32, 8), B256, 0, stream>>>(sa_wq, sa_wk, sa_wv, sa_wo,
                                             ca_wq, ca_wk, ca_wv, ca_wo, W);
  wtr<<<dim3(128, 32), B256, 0, stream>>>(fc_w1, w1T, 1024, 4096);
  wtr<<<dim3(32, 128), B256, 0, stream>>>(fc_w2, w2T, 4096, 1024);

  // ---- LNs for self-QKV and cross-KV (independent inputs) ----
  ln_k<<<4096, B256, 0, stream>>>(x, ln1_g, ln1_b, t0);
  ln_k<<<4096, B256, 0, stream>>>(kv_in, ln2_g, ln2_b, kvln);
  // merged self-QKV + cross-KV: 320 blocks on the 256x256 structure
  gemm256_dual<<<dim3(320), dim3(512), 0, stream>>>(
      t0, W, qkvb, vts, kvln, W + 5 * MB, kb, vtc);

  // ---- self attention ----
  flash8<true><<<dim3(8, 64), B256, 0, stream>>>(
      qkvb, 2048, qkvb + 1024, 2048, vts, ctx);
  // self O-proj: split-K x4 (K slices of 256, lda 1024), bf16 partials in hb
  gemm256<5><<<dim3(4, 16, 4), dim3(512), 0, stream>>>(
      ctx, W + 3 * MB, nullptr, partsO, 4096, 1024, 256, 1024);
  comb4<0><<<4096, B256, 0, stream>>>(
      (const ushort4*)(partsO + 0 * PSL), (const ushort4*)(partsO + 1 * PSL),
      (const ushort4*)(partsO + 2 * PSL), (const ushort4*)(partsO + 3 * PSL),
      (const float4*)x, nullptr, z);

  // ---- cross attention ----
  ln_k<<<4096, B256, 0, stream>>>(z, ln2_g, ln2_b, t0);
  // cross-Q: split-K x4, bf16 partials -> qb
  gemm256<5><<<dim3(4, 16, 4), dim3(512), 0, stream>>>(
      t0, W + 4 * MB, nullptr, partsO, 4096, 1024, 256, 1024);
  comb4<1><<<4096, B256, 0, stream>>>(
      (const ushort4*)(partsO + 0 * PSL), (const ushort4*)(partsO + 1 * PSL),
      (const ushort4*)(partsO + 2 * PSL), (const ushort4*)(partsO + 3 * PSL),
      nullptr, nullptr, qb);
  flash8<false><<<dim3(8, 64), B256, 0, stream>>>(
      qb, 1024, kb, 1024, vtc, ctx);
  // cross O-proj: split-K x4, combine adds z in place
  gemm256<5><<<dim3(4, 16, 4), dim3(512), 0, stream>>>(
      ctx, W + 7 * MB, nullptr, partsO, 4096, 1024, 256, 1024);
  comb4<0><<<4096, B256, 0, stream>>>(
      (const ushort4*)(partsO + 0 * PSL), (const ushort4*)(partsO + 1 * PSL),
      (const ushort4*)(partsO + 2 * PSL), (const ushort4*)(partsO + 3 * PSL),
      (const float4*)z, nullptr, z);

  // ---- FFN ----
  ln_k<<<4096, B256, 0, stream>>>(z, ln3_g, ln3_b, t0);
  gemm256<2><<<dim3(16, 16), dim3(512), 0, stream>>>(
      t0, w1T, fc_b1, hb, 4096, 4096, 1024, 1024);
  // FFN-down: split-K x4 (K slices of 1024, lda 4096), partials at 56 MB
  gemm256<5><<<dim3(4, 16, 4), dim3(512), 0, stream>>>(
      hb, w2T, nullptr, partsb, 4096, 1024, 1024, 4096);
  comb4<2><<<4096, B256, 0, stream>>>(
      (const ushort4*)(partsb + 0 * PSL), (const ushort4*)(partsb + 1 * PSL),
      (const ushort4*)(partsb + 2 * PSL), (const ushort4*)(partsb + 3 * PSL),
      (const float4*)z, (const float4*)fc_b2, (float4*)d_out);
}

// Round 26
// 330.902 us; speedup vs baseline: 1.0539x; 1.0539x over previous
//
#include <hip/hip_runtime.h>
#include <hip/hip_bf16.h>

typedef __attribute__((ext_vector_type(8))) short short8;
typedef __attribute__((ext_vector_type(4))) float f32x4;
using bf16 = __hip_bfloat16;

__device__ __forceinline__ void gload16(const void* g, void* l) {
  __builtin_amdgcn_global_load_lds(
      (const __attribute__((address_space(1))) void*)g,
      (__attribute__((address_space(3))) void*)l, 16, 0, 0);
}

__device__ __forceinline__ short f2bf(float f) {
  bf16 h = __float2bfloat16(f);
  short s;
  __builtin_memcpy(&s, &h, 2);
  return s;
}

__device__ __forceinline__ float bf2f(unsigned short u) {
  unsigned int x = ((unsigned int)u) << 16;
  float f;
  __builtin_memcpy(&f, &x, 4);
  return f;
}

// ------------- batched weight transpose fp32[1024][1024] -> bf16[C][R] ------
__global__ __launch_bounds__(256)
void wtr8(const float* w0, const float* w1, const float* w2, const float* w3,
          const float* w4, const float* w5, const float* w6, const float* w7,
          bf16* __restrict__ Wout) {
  __shared__ float tile[32][33];
  const float* w;
  switch (blockIdx.z) {
    case 0: w = w0; break; case 1: w = w1; break;
    case 2: w = w2; break; case 3: w = w3; break;
    case 4: w = w4; break; case 5: w = w5; break;
    case 6: w = w6; break; default: w = w7; break;
  }
  bf16* wt = Wout + (size_t)blockIdx.z * 1024 * 1024;
  const int tx = threadIdx.x & 31, ty = threadIdx.x >> 5;
  const int c0 = blockIdx.x * 32, r0 = blockIdx.y * 32;
#pragma unroll
  for (int i = 0; i < 4; ++i)
    tile[ty * 4 + i][tx] = w[(size_t)(r0 + ty * 4 + i) * 1024 + c0 + tx];
  __syncthreads();
#pragma unroll
  for (int i = 0; i < 4; ++i) {
    const int cc = ty * 4 + i;
    wt[(size_t)(c0 + cc) * 1024 + r0 + tx] = __float2bfloat16(tile[tx][cc]);
  }
}

// ---------------- weight transpose fp32[R][C] -> bf16[C][R] ----------------
__global__ __launch_bounds__(256)
void wtr(const float* __restrict__ w, bf16* __restrict__ wt, int R, int C) {
  __shared__ float tile[32][33];
  const int tx = threadIdx.x & 31, ty = threadIdx.x >> 5;
  const int c0 = blockIdx.x * 32, r0 = blockIdx.y * 32;
#pragma unroll
  for (int i = 0; i < 4; ++i)
    tile[ty * 4 + i][tx] = w[(size_t)(r0 + ty * 4 + i) * C + c0 + tx];
  __syncthreads();
#pragma unroll
  for (int i = 0; i < 4; ++i) {
    const int cc = ty * 4 + i;
    wt[(size_t)(c0 + cc) * R + r0 + tx] = __float2bfloat16(tile[tx][cc]);
  }
}

// ---------------- LayerNorm fp32 row(1024) -> bf16 ----------------
__global__ __launch_bounds__(256)
void ln_k(const float* __restrict__ x, const float* __restrict__ g,
          const float* __restrict__ b, bf16* __restrict__ y) {
  const int row = blockIdx.x, t = threadIdx.x;
  const int wv = t >> 6, l = t & 63;
  const float4 v = reinterpret_cast<const float4*>(x + (size_t)row * 1024)[t];
  float s = v.x + v.y + v.z + v.w;
  float s2 = v.x * v.x + v.y * v.y + v.z * v.z + v.w * v.w;
#pragma unroll
  for (int m = 1; m < 64; m <<= 1) {
    s += __shfl_xor(s, m, 64);
    s2 += __shfl_xor(s2, m, 64);
  }
  __shared__ float ps[4], ps2[4];
  if (l == 0) { ps[wv] = s; ps2[wv] = s2; }
  __syncthreads();
  s = ps[0] + ps[1] + ps[2] + ps[3];
  s2 = ps2[0] + ps2[1] + ps2[2] + ps2[3];
  const float mean = s * (1.f / 1024.f);
  const float var = s2 * (1.f / 1024.f) - mean * mean;
  const float rs = rsqrtf(var + 1e-5f);
  const float4 gg = reinterpret_cast<const float4*>(g)[t];
  const float4 bb = reinterpret_cast<const float4*>(b)[t];
  ushort4 o;
  o.x = (unsigned short)f2bf((v.x - mean) * rs * gg.x + bb.x);
  o.y = (unsigned short)f2bf((v.y - mean) * rs * gg.y + bb.y);
  o.z = (unsigned short)f2bf((v.z - mean) * rs * gg.z + bb.z);
  o.w = (unsigned short)f2bf((v.w - mean) * rs * gg.w + bb.w);
  reinterpret_cast<ushort4*>(y + (size_t)row * 1024)[t] = o;
}

// ---- FFN-down combine: out = p0+p1+p2+p3 (bf16) + res + bias (f32) --------
__global__ __launch_bounds__(256)
void ffn_add4b(const ushort4* __restrict__ p0, const ushort4* __restrict__ p1,
               const ushort4* __restrict__ p2, const ushort4* __restrict__ p3,
               const float4* __restrict__ res, const float4* __restrict__ bias,
               float4* __restrict__ out) {
  const size_t i = (size_t)blockIdx.x * 256 + threadIdx.x;
  const ushort4 a = p0[i], b = p1[i], c = p2[i], d = p3[i];
  const float4 r = res[i];
  const float4 g = bias[i & 255];  // 1024 cols / 4 = 256 float4 per row
  float4 o;
  o.x = (bf2f(a.x) + bf2f(b.x)) + (bf2f(c.x) + bf2f(d.x)) + r.x + g.x;
  o.y = (bf2f(a.y) + bf2f(b.y)) + (bf2f(c.y) + bf2f(d.y)) + r.y + g.y;
  o.z = (bf2f(a.z) + bf2f(b.z)) + (bf2f(c.z) + bf2f(d.z)) + r.z + g.z;
  o.w = (bf2f(a.w) + bf2f(b.w)) + (bf2f(c.w) + bf2f(d.w)) + r.w + g.w;
  out[i] = o;
}

// ---- GEMM: C[M,N] = A[M,K](bf16) @ B(K,N) given BT[N,K](bf16) ----
// BM=64: dual-barrier counted-vmcnt 2-stage (48 KB -> 3 blk/CU).
// BM=128: classic 2-stage dbuf. 4 waves (2x2). T2 XOR-swizzled LDS.
// EPI: 0 = bf16 out; 1 = f32 out + residual; 2 = bf16 relu(acc+bias);
//      3 = f32 out + residual + bias;
//      4 = split: col<nv0 -> bf16 out (ld=nv0); col>=nv0 -> V^T store to vtp
template <int BM, int EPI>
__global__ __launch_bounds__(256, 2)
void gemm_bt(const bf16* __restrict__ A, const bf16* __restrict__ BT,
             const float* bias, const float* res, void* outp,
             int M, int N, int K, bf16* vtp, int nv0) {
  constexpr int WM = BM / 32;     // m-frags per wave
  constexpr int APASS = BM / 32;  // staging passes for A tile
  __shared__ alignas(16) short al[2][BM * 64];
  __shared__ alignas(16) short bl[2][128 * 64];
  const int t = threadIdx.x;
  const int gx = N >> 7;
  const int nwg = gridDim.x * gridDim.y;
  int id = blockIdx.y * gridDim.x + blockIdx.x;
  id = (id & 7) * (nwg >> 3) + (id >> 3);  // XCD-chunked swizzle (nwg%8==0)
  const int bx = id % gx, by = id / gx;
  const int m0 = by * BM, n0 = bx * 128;
  const int wv = t >> 6, l = t & 63, lr = l & 15, lk = l >> 4;
  const int wr = wv >> 1, wc = wv & 1;
  const int tr = t >> 3, tc = (t & 7) * 8;
  const int tcs = (((t & 7) ^ (tr & 7)) * 8);
  const int cro0 = ((lk ^ (lr & 7)) * 8);
  const int cro1 = (((4 + lk) ^ (lr & 7)) * 8);

  f32x4 acc[WM][4];
#pragma unroll
  for (int i = 0; i < WM; ++i)
#pragma unroll
    for (int j = 0; j < 4; ++j) acc[i][j] = (f32x4)0.f;

#define STAGE(buf, k0)                                                        \
  do {                                                                        \
    _Pragma("unroll") for (int it = 0; it < APASS; ++it) {                    \
      const int row = it * 32 + tr;                                           \
      gload16(A + (size_t)(m0 + row) * K + (k0) + tcs,                        \
              (char*)&al[buf][row * 64 + tc]);                                \
    }                                                                         \
    _Pragma("unroll") for (int it = 0; it < 4; ++it) {                        \
      const int row = it * 32 + tr;                                           \
      gload16(BT + (size_t)(n0 + row) * K + (k0) + tcs,                       \
              (char*)&bl[buf][row * 64 + tc]);                                \
    }                                                                         \
  } while (0)

#define COMPUTE(cur)                                                          \
  do {                                                                        \
    _Pragma("unroll") for (int ks = 0; ks < 2; ++ks) {                        \
      const int cro = ks ? cro1 : cro0;                                       \
      short8 af[WM], bfv[4];                                                  \
      _Pragma("unroll") for (int m = 0; m < WM; ++m) af[m] =                  \
          *reinterpret_cast<const short8*>(                                   \
              &al[cur][(wr * (BM / 2) + m * 16 + lr) * 64 + cro]);            \
      _Pragma("unroll") for (int n = 0; n < 4; ++n) bfv[n] =                  \
          *reinterpret_cast<const short8*>(                                   \
              &bl[cur][(wc * 64 + n * 16 + lr) * 64 + cro]);                  \
      _Pragma("unroll") for (int m = 0; m < WM; ++m)                          \
          _Pragma("unroll") for (int n = 0; n < 4; ++n) acc[m][n] =           \
              __builtin_amdgcn_mfma_f32_16x16x32_bf16(af[m], bfv[n],          \
                                                      acc[m][n], 0, 0, 0);    \
    }                                                                         \
  } while (0)

  const int nt = K >> 6;
  if constexpr (BM == 64) {
    STAGE(0, 0);
    STAGE(1, 64);
    for (int tk = 0; tk < nt; ++tk) {
      const int cur = tk & 1;
      if (tk < nt - 1)
        asm volatile("s_waitcnt vmcnt(6)" ::: "memory");
      else
        asm volatile("s_waitcnt vmcnt(0)" ::: "memory");
      __builtin_amdgcn_s_barrier();
      COMPUTE(cur);
      if (tk + 2 < nt) {
        asm volatile("s_waitcnt lgkmcnt(0)" ::: "memory");
        __builtin_amdgcn_s_barrier();
        STAGE(cur, (tk + 2) << 6);
      }
    }
  } else {
    STAGE(0, 0);
    asm volatile("s_waitcnt vmcnt(0)" ::: "memory");
    __syncthreads();
    for (int tk = 0; tk < nt; ++tk) {
      const int cur = tk & 1;
      if (tk + 1 < nt) STAGE(cur ^ 1, (tk + 1) << 6);
      COMPUTE(cur);
      asm volatile("s_waitcnt vmcnt(0)" ::: "memory");
      __syncthreads();
    }
  }
#undef STAGE
#undef COMPUTE

  const int r0 = m0 + wr * (BM / 2), c0 = n0 + wc * 64;
  if constexpr (EPI == 4) {
#pragma unroll
    for (int m = 0; m < WM; ++m) {
      const int rowb = r0 + m * 16 + lk * 4;
      const int bb = rowb >> 10, s0 = rowb & 1023;
#pragma unroll
      for (int n = 0; n < 4; ++n) {
        const int col = c0 + n * 16 + lr;
        if (col < nv0) {
#pragma unroll
          for (int r = 0; r < 4; ++r)
            ((bf16*)outp)[(size_t)(rowb + r) * nv0 + col] =
                __float2bfloat16(acc[m][n][r]);
        } else {
          ushort4 u;
          u.x = (unsigned short)f2bf(acc[m][n][0]);
          u.y = (unsigned short)f2bf(acc[m][n][1]);
          u.z = (unsigned short)f2bf(acc[m][n][2]);
          u.w = (unsigned short)f2bf(acc[m][n][3]);
          const size_t vidx = ((size_t)bb * 1024 + (col - nv0)) * 1024 + s0;
          *reinterpret_cast<ushort4*>(vtp + vidx) = u;
        }
      }
    }
  } else {
#pragma unroll
    for (int m = 0; m < WM; ++m)
#pragma unroll
      for (int n = 0; n < 4; ++n) {
        const int col = c0 + n * 16 + lr;
#pragma unroll
        for (int r = 0; r < 4; ++r) {
          const int row = r0 + m * 16 + lk * 4 + r;
          const size_t idx = (size_t)row * N + col;
          float v = acc[m][n][r];
          if (EPI == 0) {
            ((bf16*)outp)[idx] = __float2bfloat16(v);
          } else if (EPI == 1) {
            ((float*)outp)[idx] = res[idx] + v;
          } else if (EPI == 2) {
            v += bias[col];
            ((bf16*)outp)[idx] = __float2bfloat16(fmaxf(v, 0.f));
          } else {
            ((float*)outp)[idx] = res[idx] + v + bias[col];
          }
        }
      }
  }
}

// ---- GEMM 256x256 tile, 8 waves (2Mx4N), dual-barrier counted vmcnt(8) ----
// LDS 128 KB (2-stage). Per wave: 128x64 output, 64 MFMA per K-step.
// lda = leading dim of A/BT rows (exceeds K for split-K slices).
// EPI: 2 = bf16 relu(acc+bias) to outp ld N (FFN-up);
//      5 = split-K partial: slice z reads cols [z*K,(z+1)*K), writes BF16
//          partial to (bf16*)outp + z*M*N
template <int EPI>
__global__ __launch_bounds__(512, 1)
void gemm256(const bf16* __restrict__ A, const bf16* __restrict__ BT,
             const float* __restrict__ bias, void* __restrict__ outp,
             int M, int N, int K, int lda) {
  __shared__ alignas(16) short al[2][256 * 64];
  __shared__ alignas(16) short bl[2][256 * 64];
  const int t = threadIdx.x;
  const int gx = N >> 8;
  const int nwg = gridDim.x * gridDim.y;
  int id = blockIdx.y * gridDim.x + blockIdx.x;
  id = (id & 7) * (nwg >> 3) + (id >> 3);  // XCD-chunked (nwg%8==0)
  const int bx = id % gx, by = id / gx;
  const int m0 = by * 256, n0 = bx * 256;
  const int wid = t >> 6, l = t & 63, lr = l & 15, lk = l >> 4;
  const int wm = wid >> 2, wn = wid & 3;
  const int tr = t >> 3, tc = (t & 7) * 8;
  const int tcs = (((t & 7) ^ (tr & 7)) * 8);
  const int cro0 = ((lk ^ (lr & 7)) * 8);
  const int cro1 = (((4 + lk) ^ (lr & 7)) * 8);

  const bf16* Ab = (EPI == 5) ? A + (size_t)blockIdx.z * K : A;
  const bf16* BTb = (EPI == 5) ? BT + (size_t)blockIdx.z * K : BT;

  f32x4 acc[8][4];
#pragma unroll
  for (int i = 0; i < 8; ++i)
#pragma unroll
    for (int j = 0; j < 4; ++j) acc[i][j] = (f32x4)0.f;

#define STAGE2(buf, k0)                                                       \
  do {                                                                        \
    _Pragma("unroll") for (int it = 0; it < 4; ++it) {                        \
      const int row = it * 64 + tr;                                           \
      gload16(Ab + (size_t)(m0 + row) * lda + (k0) + tcs,                     \
              (char*)&al[buf][row * 64 + tc]);                                \
    }                                                                         \
    _Pragma("unroll") for (int it = 0; it < 4; ++it) {                        \
      const int row = it * 64 + tr;                                           \
      gload16(BTb + (size_t)(n0 + row) * lda + (k0) + tcs,                    \
              (char*)&bl[buf][row * 64 + tc]);                                \
    }                                                                         \
  } while (0)

#define COMPUTE2(cur)                                                         \
  do {                                                                        \
    _Pragma("unroll") for (int ks = 0; ks < 2; ++ks) {                        \
      const int cro = ks ? cro1 : cro0;                                       \
      short8 af[8], bfv[4];                                                   \
      _Pragma("unroll") for (int m = 0; m < 8; ++m) af[m] =                   \
          *reinterpret_cast<const short8*>(                                   \
              &al[cur][(wm * 128 + m * 16 + lr) * 64 + cro]);                 \
      _Pragma("unroll") for (int n = 0; n < 4; ++n) bfv[n] =                  \
          *reinterpret_cast<const short8*>(                                   \
              &bl[cur][(wn * 64 + n * 16 + lr) * 64 + cro]);                  \
      _Pragma("unroll") for (int m = 0; m < 8; ++m)                           \
          _Pragma("unroll") for (int n = 0; n < 4; ++n) acc[m][n] =           \
              __builtin_amdgcn_mfma_f32_16x16x32_bf16(af[m], bfv[n],          \
                                                      acc[m][n], 0, 0, 0);    \
    }                                                                         \
  } while (0)

  const int nt = K >> 6;
  STAGE2(0, 0);
  STAGE2(1, 64);
  for (int tk = 0; tk < nt; ++tk) {
    const int cur = tk & 1;
    if (tk < nt - 1)
      asm volatile("s_waitcnt vmcnt(8)" ::: "memory");
    else
      asm volatile("s_waitcnt vmcnt(0)" ::: "memory");
    __builtin_amdgcn_s_barrier();
    COMPUTE2(cur);
    if (tk + 2 < nt) {
      asm volatile("s_waitcnt lgkmcnt(0)" ::: "memory");
      __builtin_amdgcn_s_barrier();
      STAGE2(cur, (tk + 2) << 6);
    }
  }
#undef STAGE2
#undef COMPUTE2

  const int r0 = m0 + wm * 128, c0 = n0 + wn * 64;
  if constexpr (EPI == 2) {
#pragma unroll
    for (int m = 0; m < 8; ++m)
#pragma unroll
      for (int n = 0; n < 4; ++n) {
        const int col = c0 + n * 16 + lr;
        const float bcol = bias[col];
#pragma unroll
        for (int r = 0; r < 4; ++r) {
          const int row = r0 + m * 16 + lk * 4 + r;
          const float v = acc[m][n][r] + bcol;
          ((bf16*)outp)[(size_t)row * N + col] =
              __float2bfloat16(fmaxf(v, 0.f));
        }
      }
  } else {
    bf16* po = (bf16*)outp + (size_t)blockIdx.z * M * N;
#pragma unroll
    for (int m = 0; m < 8; ++m)
#pragma unroll
      for (int n = 0; n < 4; ++n) {
        const int col = c0 + n * 16 + lr;
#pragma unroll
        for (int r = 0; r < 4; ++r) {
          const int row = r0 + m * 16 + lk * 4 + r;
          po[(size_t)row * N + col] = __float2bfloat16(acc[m][n][r]);
        }
      }
  }
}

// ---- Merged QKV + cross-KV on the 256x256 structure (320 blocks) ----------
__global__ __launch_bounds__(512, 1)
void gemm256_dual(const bf16* __restrict__ A0, const bf16* __restrict__ BT0,
                  bf16* __restrict__ out0, bf16* __restrict__ vt0,
                  const bf16* __restrict__ A1, const bf16* __restrict__ BT1,
                  bf16* __restrict__ out1, bf16* __restrict__ vt1) {
  __shared__ alignas(16) short al[2][256 * 64];
  __shared__ alignas(16) short bl[2][256 * 64];
  const int t = threadIdx.x;
  const int raw = blockIdx.x;
  const int id = (raw & 7) * 40 + (raw >> 3);  // 320 = 8*40, bijective
  const bf16 *A, *BT;
  bf16 *outp, *vtp;
  int nv0, gx, pid;
  if (id < 192) {
    A = A0; BT = BT0; outp = out0; vtp = vt0; nv0 = 2048; gx = 12; pid = id;
  } else {
    A = A1; BT = BT1; outp = out1; vtp = vt1; nv0 = 1024; gx = 8;
    pid = id - 192;
  }
  const int K = 1024;
  const int bx = pid % gx, by = pid / gx;
  const int m0 = by * 256, n0 = bx * 256;
  const int wid = t >> 6, l = t & 63, lr = l & 15, lk = l >> 4;
  const int wm = wid >> 2, wn = wid & 3;
  const int tr = t >> 3, tc = (t & 7) * 8;
  const int tcs = (((t & 7) ^ (tr & 7)) * 8);
  const int cro0 = ((lk ^ (lr & 7)) * 8);
  const int cro1 = (((4 + lk) ^ (lr & 7)) * 8);

  f32x4 acc[8][4];
#pragma unroll
  for (int i = 0; i < 8; ++i)
#pragma unroll
    for (int j = 0; j < 4; ++j) acc[i][j] = (f32x4)0.f;

#define STAGE2(buf, k0)                                                       \
  do {                                                                        \
    _Pragma("unroll") for (int it = 0; it < 4; ++it) {                        \
      const int row = it * 64 + tr;                                           \
      gload16(A + (size_t)(m0 + row) * K + (k0) + tcs,                        \
              (char*)&al[buf][row * 64 + tc]);                                \
    }                                                                         \
    _Pragma("unroll") for (int it = 0; it < 4; ++it) {                        \
      const int row = it * 64 + tr;                                           \
      gload16(BT + (size_t)(n0 + row) * K + (k0) + tcs,                       \
              (char*)&bl[buf][row * 64 + tc]);                                \
    }                                                                         \
  } while (0)

#define COMPUTE2(cur)                                                         \
  do {                                                                        \
    _Pragma("unroll") for (int ks = 0; ks < 2; ++ks) {                        \
      const int cro = ks ? cro1 : cro0;                                       \
      short8 af[8], bfv[4];                                                   \
      _Pragma("unroll") for (int m = 0; m < 8; ++m) af[m] =                   \
          *reinterpret_cast<const short8*>(                                   \
              &al[cur][(wm * 128 + m * 16 + lr) * 64 + cro]);                 \
      _Pragma("unroll") for (int n = 0; n < 4; ++n) bfv[n] =                  \
          *reinterpret_cast<const short8*>(                                   \
              &bl[cur][(wn * 64 + n * 16 + lr) * 64 + cro]);                  \
      _Pragma("unroll") for (int m = 0; m < 8; ++m)                           \
          _Pragma("unroll") for (int n = 0; n < 4; ++n) acc[m][n] =           \
              __builtin_amdgcn_mfma_f32_16x16x32_bf16(af[m], bfv[n],          \
                                                      acc[m][n], 0, 0, 0);    \
    }                                                                         \
  } while (0)

  const int nt = K >> 6;
  STAGE2(0, 0);
  STAGE2(1, 64);
  for (int tk = 0; tk < nt; ++tk) {
    const int cur = tk & 1;
    if (tk < nt - 1)
      asm volatile("s_waitcnt vmcnt(8)" ::: "memory");
    else
      asm volatile("s_waitcnt vmcnt(0)" ::: "memory");
    __builtin_amdgcn_s_barrier();
    COMPUTE2(cur);
    if (tk + 2 < nt) {
      asm volatile("s_waitcnt lgkmcnt(0)" ::: "memory");
      __builtin_amdgcn_s_barrier();
      STAGE2(cur, (tk + 2) << 6);
    }
  }
#undef STAGE2
#undef COMPUTE2

  const int r0 = m0 + wm * 128, c0 = n0 + wn * 64;
#pragma unroll
  for (int m = 0; m < 8; ++m) {
    const int rowb = r0 + m * 16 + lk * 4;
    const int bb = rowb >> 10, s0 = rowb & 1023;
#pragma unroll
    for (int n = 0; n < 4; ++n) {
      const int col = c0 + n * 16 + lr;
      if (col < nv0) {
#pragma unroll
        for (int r = 0; r < 4; ++r)
          outp[(size_t)(rowb + r) * nv0 + col] =
              __float2bfloat16(acc[m][n][r]);
      } else {
        ushort4 u;
        u.x = (unsigned short)f2bf(acc[m][n][0]);
        u.y = (unsigned short)f2bf(acc[m][n][1]);
        u.z = (unsigned short)f2bf(acc[m][n][2]);
        u.w = (unsigned short)f2bf(acc[m][n][3]);
        const size_t vidx = ((size_t)bb * 1024 + (col - nv0)) * 1024 + s0;
        *reinterpret_cast<ushort4*>(vtp + vidx) = u;
      }
    }
  }
}

// ---------------- Flash attention v8: LDS-staged K/V, 3-stage pipeline ------
template <bool CAUSAL>
__global__ __launch_bounds__(256, 2)
void flash8(const bf16* __restrict__ Qb, int ldq,
            const bf16* __restrict__ Kb, int ldk,
            const bf16* __restrict__ VTb, bf16* __restrict__ Ob) {
  __shared__ alignas(16) short kl[3][64 * 64];
  __shared__ alignas(16) short vl[3][64 * 64];
  __shared__ alignas(16) short pl[4][32 * 72];
  const int t = threadIdx.x, wv = t >> 6, l = t & 63, lr = l & 15, lk = l >> 4;
  const int raw = blockIdx.y * 8 + blockIdx.x;
  const int id = (raw & 7) * 64 + (raw >> 3);
  const int qb = id & 7, bh = id >> 3;
  const int b = bh >> 4, h = bh & 15;
  const size_t rowbase = (size_t)b * 1024;
  const int q0 = qb * 128 + wv * 32;
  const bf16* Vbase = VTb + (rowbase + h * 64) * 1024;

  const int tr = t >> 3;
  const int tcd = (t & 7) * 8;
  const int tcs = (((t & 7) ^ (tr & 7)) * 8);
  const int cro0 = ((lk ^ (lr & 7)) * 8);
  const int cro1 = (((4 + lk) ^ (lr & 7)) * 8);

  short8 qf[2][2];
#pragma unroll
  for (int m = 0; m < 2; ++m)
#pragma unroll
    for (int ks = 0; ks < 2; ++ks)
      qf[m][ks] = *reinterpret_cast<const short8*>(
          Qb + (rowbase + q0 + m * 16 + lr) * ldq + h * 64 + ks * 32 + lk * 8);

  short8 ones;
#pragma unroll
  for (int j = 0; j < 8; ++j) ones[j] = (short)0x3F80;  // bf16 1.0

  f32x4 accO[2][4];
  f32x4 accL[2];
#pragma unroll
  for (int m = 0; m < 2; ++m) {
#pragma unroll
    for (int n = 0; n < 4; ++n) accO[m][n] = (f32x4)0.f;
    accL[m] = (f32x4)0.f;
  }

  const int ntb = CAUSAL ? (qb * 2 + 2) : 16;
  const int myLast = q0 >> 6;

#define FSTAGE(buf, kv0)                                                      \
  do {                                                                        \
    _Pragma("unroll") for (int it = 0; it < 2; ++it) {                        \
      const int row = it * 32 + tr;                                           \
      gload16(Kb + (rowbase + (kv0) + row) * ldk + h * 64 + tcs,              \
              (char*)&kl[buf][row * 64 + tcd]);                               \
    }                                                                         \
    _Pragma("unroll") for (int it = 0; it < 2; ++it) {                        \
      const int row = it * 32 + tr;                                           \
      gload16(Vbase + (size_t)row * 1024 + (kv0) + tcs,                       \
              (char*)&vl[buf][row * 64 + tcd]);                               \
    }                                                                         \
  } while (0)

  FSTAGE(0, 0);
  FSTAGE(1, 64);
  int cur = 0;
  for (int tk = 0; tk < ntb; ++tk) {
    if (tk < ntb - 1)
      asm volatile("s_waitcnt vmcnt(4)" ::: "memory");
    else
      asm volatile("s_waitcnt vmcnt(0)" ::: "memory");
    __builtin_amdgcn_s_barrier();
    if (tk + 2 < ntb) {
      int stg = cur + 2;
      if (stg >= 3) stg -= 3;
      FSTAGE(stg, (tk + 2) << 6);
    }
    if (!CAUSAL || tk <= myLast) {
      const int kv0 = tk * 64;
      const bool needmask = CAUSAL && (tk == myLast);
      f32x4 sa[2][4];
#pragma unroll
      for (int m = 0; m < 2; ++m)
#pragma unroll
        for (int n = 0; n < 4; ++n) sa[m][n] = (f32x4)0.f;
#pragma unroll
      for (int ks = 0; ks < 2; ++ks) {
        const int cro = ks ? cro1 : cro0;
        short8 kf[4];
#pragma unroll
        for (int n = 0; n < 4; ++n)
          kf[n] = *reinterpret_cast<const short8*>(
              &kl[cur][(n * 16 + lr) * 64 + cro]);
        __builtin_amdgcn_s_setprio(1);
#pragma unroll
        for (int m = 0; m < 2; ++m)
#pragma unroll
          for (int n = 0; n < 4; ++n)
            sa[m][n] = __builtin_amdgcn_mfma_f32_16x16x32_bf16(
                qf[m][ks], kf[n], sa[m][n], 0, 0, 0);
        __builtin_amdgcn_s_setprio(0);
      }
#pragma unroll
      for (int m = 0; m < 2; ++m) {
#pragma unroll
        for (int r = 0; r < 4; ++r) {
          const int row = q0 + m * 16 + lk * 4 + r;
          float s0 = sa[m][0][r] * 0.125f, s1 = sa[m][1][r] * 0.125f;
          float s2 = sa[m][2][r] * 0.125f, s3 = sa[m][3][r] * 0.125f;
          if (needmask) {
            if (kv0 + 0 + lr > row) s0 = -1e30f;
            if (kv0 + 16 + lr > row) s1 = -1e30f;
            if (kv0 + 32 + lr > row) s2 = -1e30f;
            if (kv0 + 48 + lr > row) s3 = -1e30f;
          }
          const float p0 = __expf(s0), p1 = __expf(s1);
          const float p2 = __expf(s2), p3 = __expf(s3);
          const int prow = m * 16 + lk * 4 + r;
          pl[wv][prow * 72 + lr + 0] = f2bf(p0);
          pl[wv][prow * 72 + lr + 16] = f2bf(p1);
          pl[wv][prow * 72 + lr + 32] = f2bf(p2);
          pl[wv][prow * 72 + lr + 48] = f2bf(p3);
        }
      }
#pragma unroll
      for (int ks = 0; ks < 2; ++ks) {
        const int cro = ks ? cro1 : cro0;
        short8 pf[2], vf[4];
#pragma unroll
        for (int m = 0; m < 2; ++m)
          pf[m] = *reinterpret_cast<const short8*>(
              &pl[wv][(m * 16 + lr) * 72 + ks * 32 + lk * 8]);
#pragma unroll
        for (int n = 0; n < 4; ++n)
          vf[n] = *reinterpret_cast<const short8*>(
              &vl[cur][(n * 16 + lr) * 64 + cro]);
        __builtin_amdgcn_s_setprio(1);
#pragma unroll
        for (int m = 0; m < 2; ++m) {
#pragma unroll
          for (int n = 0; n < 4; ++n)
            accO[m][n] = __builtin_amdgcn_mfma_f32_16x16x32_bf16(
                pf[m], vf[n], accO[m][n], 0, 0, 0);
          accL[m] = __builtin_amdgcn_mfma_f32_16x16x32_bf16(
              pf[m], ones, accL[m], 0, 0, 0);
        }
        __builtin_amdgcn_s_setprio(0);
      }
    }
    cur = (cur + 1 == 3) ? 0 : cur + 1;
  }
#undef FSTAGE

#pragma unroll
  for (int m = 0; m < 2; ++m)
#pragma unroll
    for (int n = 0; n < 4; ++n)
#pragma unroll
      for (int r = 0; r < 4; ++r) {
        const int row = q0 + m * 16 + lk * 4 + r;
        const int col = n * 16 + lr;
        const float o = accO[m][n][r] / accL[m][r];
        Ob[(rowbase + row) * 1024 + h * 64 + col] = __float2bfloat16(o);
      }
}

// ---------------- launch ----------------
extern "C" void kernel_launch(void* const* d_in, const int* in_sizes, int n_in,
                              void* d_out, int out_size, void* d_ws,
                              size_t ws_size, hipStream_t stream) {
  const float* x = (const float*)d_in[0];
  const float* kv_in = (const float*)d_in[1];
  const float* sa_wq = (const float*)d_in[4];
  const float* sa_wk = (const float*)d_in[5];
  const float* sa_wv = (const float*)d_in[6];
  const float* sa_wo = (const float*)d_in[7];
  const float* ca_wq = (const float*)d_in[8];
  const float* ca_wk = (const float*)d_in[9];
  const float* ca_wv = (const float*)d_in[10];
  const float* ca_wo = (const float*)d_in[11];
  const float* fc_w1 = (const float*)d_in[12];
  const float* fc_b1 = (const float*)d_in[13];
  const float* fc_w2 = (const float*)d_in[14];
  const float* fc_b2 = (const float*)d_in[15];
  const float* ln1_g = (const float*)d_in[16];
  const float* ln1_b = (const float*)d_in[17];
  const float* ln2_g = (const float*)d_in[18];
  const float* ln2_b = (const float*)d_in[19];
  const float* ln3_g = (const float*)d_in[20];
  const float* ln3_b = (const float*)d_in[21];

  char* ws = (char*)d_ws;
  const size_t MB = 1024 * 1024;
  bf16* W = (bf16*)ws;                    // 16M elems = 32 MB
  bf16* w1T = W + 8 * MB;
  bf16* w2T = W + 12 * MB;
  float* z = (float*)(ws + 32 * MB);      // 16 MB
  bf16* t0 = (bf16*)(ws + 48 * MB);       // 8 MB
  bf16* qkvb = (bf16*)(ws + 56 * MB);     // [4096][2048] Q|K, 16 MB
  bf16* vts = (bf16*)(ws + 72 * MB);      // self V^T [4096][1024], 8 MB
  bf16* kb = (bf16*)(ws + 80 * MB);       // cross K [4096][1024], 8 MB
  bf16* vtc = (bf16*)(ws + 88 * MB);      // cross V^T [4096][1024], 8 MB
  bf16* qb = (bf16*)(ws + 96 * MB);       // 8 MB
  bf16* ctx = (bf16*)(ws + 104 * MB);     // 8 MB
  bf16* kvln = (bf16*)(ws + 112 * MB);    // 8 MB
  bf16* hb = (bf16*)(ws + 120 * MB);      // [4096][4096] 32 MB
  // FFN-down bf16 split-K partials: 4 x 8 MB over the dead attention region
  bf16* partsb = (bf16*)(ws + 56 * MB);   // 32 MB (qkvb..vtc dead by then)
  const size_t PSL = (size_t)4096 * 1024;

  const dim3 B256(256);
  wtr8<<<dim3(32, 32, 8), B256, 0, stream>>>(sa_wq, sa_wk, sa_wv, sa_wo,
                                             ca_wq, ca_wk, ca_wv, ca_wo, W);
  wtr<<<dim3(128, 32), B256, 0, stream>>>(fc_w1, w1T, 1024, 4096);
  wtr<<<dim3(32, 128), B256, 0, stream>>>(fc_w2, w2T, 4096, 1024);

  // ---- LNs for self-QKV and cross-KV (independent inputs) ----
  ln_k<<<4096, B256, 0, stream>>>(x, ln1_g, ln1_b, t0);
  ln_k<<<4096, B256, 0, stream>>>(kv_in, ln2_g, ln2_b, kvln);
  // merged self-QKV + cross-KV: 320 blocks on the 256x256 structure
  gemm256_dual<<<dim3(320), dim3(512), 0, stream>>>(
      t0, W, qkvb, vts, kvln, W + 5 * MB, kb, vtc);

  // ---- self attention ----
  flash8<true><<<dim3(8, 64), B256, 0, stream>>>(
      qkvb, 2048, qkvb + 1024, 2048, vts, ctx);
  gemm_bt<64, 1><<<dim3(8, 64), B256, 0, stream>>>(
      ctx, W + 3 * MB, nullptr, x, z, 4096, 1024, 1024, nullptr, 0);

  // ---- cross attention ----
  ln_k<<<4096, B256, 0, stream>>>(z, ln2_g, ln2_b, t0);
  gemm_bt<64, 0><<<dim3(8, 64), B256, 0, stream>>>(
      t0, W + 4 * MB, nullptr, nullptr, qb, 4096, 1024, 1024, nullptr, 0);
  flash8<false><<<dim3(8, 64), B256, 0, stream>>>(
      qb, 1024, kb, 1024, vtc, ctx);
  gemm_bt<64, 1><<<dim3(8, 64), B256, 0, stream>>>(
      ctx, W + 7 * MB, nullptr, z, z, 4096, 1024, 1024, nullptr, 0);

  // ---- FFN ----
  ln_k<<<4096, B256, 0, stream>>>(z, ln3_g, ln3_b, t0);
  gemm256<2><<<dim3(16, 16), dim3(512), 0, stream>>>(
      t0, w1T, fc_b1, hb, 4096, 4096, 1024, 1024);
  // FFN-down split-K x4 on the 256x256 structure, BF16 partials
  gemm256<5><<<dim3(4, 16, 4), dim3(512), 0, stream>>>(
      hb, w2T, nullptr, partsb, 4096, 1024, 1024, 4096);
  ffn_add4b<<<4096, B256, 0, stream>>>(
      (const ushort4*)(partsb + 0 * PSL), (const ushort4*)(partsb + 1 * PSL),
      (const ushort4*)(partsb + 2 * PSL), (const ushort4*)(partsb + 3 * PSL),
      (const float4*)z, (const float4*)fc_b2, (float4*)d_out);
}

// Round 27
// 325.677 us; speedup vs baseline: 1.0709x; 1.0160x over previous
//
#include <hip/hip_runtime.h>
#include <hip/hip_bf16.h>

typedef __attribute__((ext_vector_type(8))) short short8;
typedef __attribute__((ext_vector_type(4))) float f32x4;
using bf16 = __hip_bfloat16;

__device__ __forceinline__ void gload16(const void* g, void* l) {
  __builtin_amdgcn_global_load_lds(
      (const __attribute__((address_space(1))) void*)g,
      (__attribute__((address_space(3))) void*)l, 16, 0, 0);
}

__device__ __forceinline__ short f2bf(float f) {
  bf16 h = __float2bfloat16(f);
  short s;
  __builtin_memcpy(&s, &h, 2);
  return s;
}

__device__ __forceinline__ float bf2f(unsigned short u) {
  unsigned int x = ((unsigned int)u) << 16;
  float f;
  __builtin_memcpy(&f, &x, 4);
  return f;
}

// ------------- batched weight transpose fp32[1024][1024] -> bf16[C][R] ------
__global__ __launch_bounds__(256)
void wtr8(const float* w0, const float* w1, const float* w2, const float* w3,
          const float* w4, const float* w5, const float* w6, const float* w7,
          bf16* __restrict__ Wout) {
  __shared__ float tile[32][33];
  const float* w;
  switch (blockIdx.z) {
    case 0: w = w0; break; case 1: w = w1; break;
    case 2: w = w2; break; case 3: w = w3; break;
    case 4: w = w4; break; case 5: w = w5; break;
    case 6: w = w6; break; default: w = w7; break;
  }
  bf16* wt = Wout + (size_t)blockIdx.z * 1024 * 1024;
  const int tx = threadIdx.x & 31, ty = threadIdx.x >> 5;
  const int c0 = blockIdx.x * 32, r0 = blockIdx.y * 32;
#pragma unroll
  for (int i = 0; i < 4; ++i)
    tile[ty * 4 + i][tx] = w[(size_t)(r0 + ty * 4 + i) * 1024 + c0 + tx];
  __syncthreads();
#pragma unroll
  for (int i = 0; i < 4; ++i) {
    const int cc = ty * 4 + i;
    wt[(size_t)(c0 + cc) * 1024 + r0 + tx] = __float2bfloat16(tile[tx][cc]);
  }
}

// ---- merged transpose of fc_w1 (1024x4096) and fc_w2 (4096x1024) ----------
// z=0: wA (R=1024,C=4096) -> wtA; z=1: wB (R=4096,C=1024) -> wtB.
// Both have 4096 32x32 tiles; blockIdx.x is the linear tile id.
__global__ __launch_bounds__(256)
void wtr2(const float* __restrict__ wA, bf16* __restrict__ wtA,
          const float* __restrict__ wB, bf16* __restrict__ wtB) {
  __shared__ float tile[32][33];
  const float* w;
  bf16* wt;
  int R, C, bx, by;
  const int b = blockIdx.x;
  if (blockIdx.z == 0) {
    w = wA; wt = wtA; R = 1024; C = 4096; bx = b & 127; by = b >> 7;
  } else {
    w = wB; wt = wtB; R = 4096; C = 1024; bx = b & 31; by = b >> 5;
  }
  const int tx = threadIdx.x & 31, ty = threadIdx.x >> 5;
  const int c0 = bx * 32, r0 = by * 32;
#pragma unroll
  for (int i = 0; i < 4; ++i)
    tile[ty * 4 + i][tx] = w[(size_t)(r0 + ty * 4 + i) * C + c0 + tx];
  __syncthreads();
#pragma unroll
  for (int i = 0; i < 4; ++i) {
    const int cc = ty * 4 + i;
    wt[(size_t)(c0 + cc) * R + r0 + tx] = __float2bfloat16(tile[tx][cc]);
  }
}

// ---------------- LayerNorm fp32 row(1024) -> bf16 ----------------
__global__ __launch_bounds__(256)
void ln_k(const float* __restrict__ x, const float* __restrict__ g,
          const float* __restrict__ b, bf16* __restrict__ y) {
  const int row = blockIdx.x, t = threadIdx.x;
  const int wv = t >> 6, l = t & 63;
  const float4 v = reinterpret_cast<const float4*>(x + (size_t)row * 1024)[t];
  float s = v.x + v.y + v.z + v.w;
  float s2 = v.x * v.x + v.y * v.y + v.z * v.z + v.w * v.w;
#pragma unroll
  for (int m = 1; m < 64; m <<= 1) {
    s += __shfl_xor(s, m, 64);
    s2 += __shfl_xor(s2, m, 64);
  }
  __shared__ float ps[4], ps2[4];
  if (l == 0) { ps[wv] = s; ps2[wv] = s2; }
  __syncthreads();
  s = ps[0] + ps[1] + ps[2] + ps[3];
  s2 = ps2[0] + ps2[1] + ps2[2] + ps2[3];
  const float mean = s * (1.f / 1024.f);
  const float var = s2 * (1.f / 1024.f) - mean * mean;
  const float rs = rsqrtf(var + 1e-5f);
  const float4 gg = reinterpret_cast<const float4*>(g)[t];
  const float4 bb = reinterpret_cast<const float4*>(b)[t];
  ushort4 o;
  o.x = (unsigned short)f2bf((v.x - mean) * rs * gg.x + bb.x);
  o.y = (unsigned short)f2bf((v.y - mean) * rs * gg.y + bb.y);
  o.z = (unsigned short)f2bf((v.z - mean) * rs * gg.z + bb.z);
  o.w = (unsigned short)f2bf((v.w - mean) * rs * gg.w + bb.w);
  reinterpret_cast<ushort4*>(y + (size_t)row * 1024)[t] = o;
}

// ---- merged LayerNorm of two independent inputs (8192 rows total) ----------
__global__ __launch_bounds__(256)
void ln_k2(const float* __restrict__ x0, const float* __restrict__ g0,
           const float* __restrict__ b0, bf16* __restrict__ y0,
           const float* __restrict__ x1, const float* __restrict__ g1,
           const float* __restrict__ b1, bf16* __restrict__ y1) {
  int row = blockIdx.x;
  const float *x, *g, *b;
  bf16* y;
  if (row < 4096) {
    x = x0; g = g0; b = b0; y = y0;
  } else {
    x = x1; g = g1; b = b1; y = y1; row -= 4096;
  }
  const int t = threadIdx.x;
  const int wv = t >> 6, l = t & 63;
  const float4 v = reinterpret_cast<const float4*>(x + (size_t)row * 1024)[t];
  float s = v.x + v.y + v.z + v.w;
  float s2 = v.x * v.x + v.y * v.y + v.z * v.z + v.w * v.w;
#pragma unroll
  for (int m = 1; m < 64; m <<= 1) {
    s += __shfl_xor(s, m, 64);
    s2 += __shfl_xor(s2, m, 64);
  }
  __shared__ float ps[4], ps2[4];
  if (l == 0) { ps[wv] = s; ps2[wv] = s2; }
  __syncthreads();
  s = ps[0] + ps[1] + ps[2] + ps[3];
  s2 = ps2[0] + ps2[1] + ps2[2] + ps2[3];
  const float mean = s * (1.f / 1024.f);
  const float var = s2 * (1.f / 1024.f) - mean * mean;
  const float rs = rsqrtf(var + 1e-5f);
  const float4 gg = reinterpret_cast<const float4*>(g)[t];
  const float4 bb = reinterpret_cast<const float4*>(b)[t];
  ushort4 o;
  o.x = (unsigned short)f2bf((v.x - mean) * rs * gg.x + bb.x);
  o.y = (unsigned short)f2bf((v.y - mean) * rs * gg.y + bb.y);
  o.z = (unsigned short)f2bf((v.z - mean) * rs * gg.z + bb.z);
  o.w = (unsigned short)f2bf((v.w - mean) * rs * gg.w + bb.w);
  reinterpret_cast<ushort4*>(y + (size_t)row * 1024)[t] = o;
}

// ---- FFN-down combine: out = p0+p1+p2+p3 (bf16) + res + bias (f32) --------
__global__ __launch_bounds__(256)
void ffn_add4b(const ushort4* __restrict__ p0, const ushort4* __restrict__ p1,
               const ushort4* __restrict__ p2, const ushort4* __restrict__ p3,
               const float4* __restrict__ res, const float4* __restrict__ bias,
               float4* __restrict__ out) {
  const size_t i = (size_t)blockIdx.x * 256 + threadIdx.x;
  const ushort4 a = p0[i], b = p1[i], c = p2[i], d = p3[i];
  const float4 r = res[i];
  const float4 g = bias[i & 255];  // 1024 cols / 4 = 256 float4 per row
  float4 o;
  o.x = (bf2f(a.x) + bf2f(b.x)) + (bf2f(c.x) + bf2f(d.x)) + r.x + g.x;
  o.y = (bf2f(a.y) + bf2f(b.y)) + (bf2f(c.y) + bf2f(d.y)) + r.y + g.y;
  o.z = (bf2f(a.z) + bf2f(b.z)) + (bf2f(c.z) + bf2f(d.z)) + r.z + g.z;
  o.w = (bf2f(a.w) + bf2f(b.w)) + (bf2f(c.w) + bf2f(d.w)) + r.w + g.w;
  out[i] = o;
}

// ---- GEMM: C[M,N] = A[M,K](bf16) @ B(K,N) given BT[N,K](bf16) ----
// BM=64: dual-barrier counted-vmcnt 2-stage (48 KB -> 3 blk/CU).
// BM=128: classic 2-stage dbuf. 4 waves (2x2). T2 XOR-swizzled LDS.
// EPI: 0 = bf16 out; 1 = f32 out + residual; 2 = bf16 relu(acc+bias);
//      3 = f32 out + residual + bias;
//      4 = split: col<nv0 -> bf16 out (ld=nv0); col>=nv0 -> V^T store to vtp
template <int BM, int EPI>
__global__ __launch_bounds__(256, 2)
void gemm_bt(const bf16* __restrict__ A, const bf16* __restrict__ BT,
             const float* bias, const float* res, void* outp,
             int M, int N, int K, bf16* vtp, int nv0) {
  constexpr int WM = BM / 32;     // m-frags per wave
  constexpr int APASS = BM / 32;  // staging passes for A tile
  __shared__ alignas(16) short al[2][BM * 64];
  __shared__ alignas(16) short bl[2][128 * 64];
  const int t = threadIdx.x;
  const int gx = N >> 7;
  const int nwg = gridDim.x * gridDim.y;
  int id = blockIdx.y * gridDim.x + blockIdx.x;
  id = (id & 7) * (nwg >> 3) + (id >> 3);  // XCD-chunked swizzle (nwg%8==0)
  const int bx = id % gx, by = id / gx;
  const int m0 = by * BM, n0 = bx * 128;
  const int wv = t >> 6, l = t & 63, lr = l & 15, lk = l >> 4;
  const int wr = wv >> 1, wc = wv & 1;
  const int tr = t >> 3, tc = (t & 7) * 8;
  const int tcs = (((t & 7) ^ (tr & 7)) * 8);
  const int cro0 = ((lk ^ (lr & 7)) * 8);
  const int cro1 = (((4 + lk) ^ (lr & 7)) * 8);

  f32x4 acc[WM][4];
#pragma unroll
  for (int i = 0; i < WM; ++i)
#pragma unroll
    for (int j = 0; j < 4; ++j) acc[i][j] = (f32x4)0.f;

#define STAGE(buf, k0)                                                        \
  do {                                                                        \
    _Pragma("unroll") for (int it = 0; it < APASS; ++it) {                    \
      const int row = it * 32 + tr;                                           \
      gload16(A + (size_t)(m0 + row) * K + (k0) + tcs,                        \
              (char*)&al[buf][row * 64 + tc]);                                \
    }                                                                         \
    _Pragma("unroll") for (int it = 0; it < 4; ++it) {                        \
      const int row = it * 32 + tr;                                           \
      gload16(BT + (size_t)(n0 + row) * K + (k0) + tcs,                       \
              (char*)&bl[buf][row * 64 + tc]);                                \
    }                                                                         \
  } while (0)

#define COMPUTE(cur)                                                          \
  do {                                                                        \
    _Pragma("unroll") for (int ks = 0; ks < 2; ++ks) {                        \
      const int cro = ks ? cro1 : cro0;                                       \
      short8 af[WM], bfv[4];                                                  \
      _Pragma("unroll") for (int m = 0; m < WM; ++m) af[m] =                  \
          *reinterpret_cast<const short8*>(                                   \
              &al[cur][(wr * (BM / 2) + m * 16 + lr) * 64 + cro]);            \
      _Pragma("unroll") for (int n = 0; n < 4; ++n) bfv[n] =                  \
          *reinterpret_cast<const short8*>(                                   \
              &bl[cur][(wc * 64 + n * 16 + lr) * 64 + cro]);                  \
      _Pragma("unroll") for (int m = 0; m < WM; ++m)                          \
          _Pragma("unroll") for (int n = 0; n < 4; ++n) acc[m][n] =           \
              __builtin_amdgcn_mfma_f32_16x16x32_bf16(af[m], bfv[n],          \
                                                      acc[m][n], 0, 0, 0);    \
    }                                                                         \
  } while (0)

  const int nt = K >> 6;
  if constexpr (BM == 64) {
    STAGE(0, 0);
    STAGE(1, 64);
    for (int tk = 0; tk < nt; ++tk) {
      const int cur = tk & 1;
      if (tk < nt - 1)
        asm volatile("s_waitcnt vmcnt(6)" ::: "memory");
      else
        asm volatile("s_waitcnt vmcnt(0)" ::: "memory");
      __builtin_amdgcn_s_barrier();
      COMPUTE(cur);
      if (tk + 2 < nt) {
        asm volatile("s_waitcnt lgkmcnt(0)" ::: "memory");
        __builtin_amdgcn_s_barrier();
        STAGE(cur, (tk + 2) << 6);
      }
    }
  } else {
    STAGE(0, 0);
    asm volatile("s_waitcnt vmcnt(0)" ::: "memory");
    __syncthreads();
    for (int tk = 0; tk < nt; ++tk) {
      const int cur = tk & 1;
      if (tk + 1 < nt) STAGE(cur ^ 1, (tk + 1) << 6);
      COMPUTE(cur);
      asm volatile("s_waitcnt vmcnt(0)" ::: "memory");
      __syncthreads();
    }
  }
#undef STAGE
#undef COMPUTE

  const int r0 = m0 + wr * (BM / 2), c0 = n0 + wc * 64;
  if constexpr (EPI == 4) {
#pragma unroll
    for (int m = 0; m < WM; ++m) {
      const int rowb = r0 + m * 16 + lk * 4;
      const int bb = rowb >> 10, s0 = rowb & 1023;
#pragma unroll
      for (int n = 0; n < 4; ++n) {
        const int col = c0 + n * 16 + lr;
        if (col < nv0) {
#pragma unroll
          for (int r = 0; r < 4; ++r)
            ((bf16*)outp)[(size_t)(rowb + r) * nv0 + col] =
                __float2bfloat16(acc[m][n][r]);
        } else {
          ushort4 u;
          u.x = (unsigned short)f2bf(acc[m][n][0]);
          u.y = (unsigned short)f2bf(acc[m][n][1]);
          u.z = (unsigned short)f2bf(acc[m][n][2]);
          u.w = (unsigned short)f2bf(acc[m][n][3]);
          const size_t vidx = ((size_t)bb * 1024 + (col - nv0)) * 1024 + s0;
          *reinterpret_cast<ushort4*>(vtp + vidx) = u;
        }
      }
    }
  } else {
#pragma unroll
    for (int m = 0; m < WM; ++m)
#pragma unroll
      for (int n = 0; n < 4; ++n) {
        const int col = c0 + n * 16 + lr;
#pragma unroll
        for (int r = 0; r < 4; ++r) {
          const int row = r0 + m * 16 + lk * 4 + r;
          const size_t idx = (size_t)row * N + col;
          float v = acc[m][n][r];
          if (EPI == 0) {
            ((bf16*)outp)[idx] = __float2bfloat16(v);
          } else if (EPI == 1) {
            ((float*)outp)[idx] = res[idx] + v;
          } else if (EPI == 2) {
            v += bias[col];
            ((bf16*)outp)[idx] = __float2bfloat16(fmaxf(v, 0.f));
          } else {
            ((float*)outp)[idx] = res[idx] + v + bias[col];
          }
        }
      }
  }
}

// ---- GEMM 256x256 tile, 8 waves (2Mx4N), dual-barrier counted vmcnt(8) ----
// LDS 128 KB (2-stage). Per wave: 128x64 output, 64 MFMA per K-step.
// lda = leading dim of A/BT rows (exceeds K for split-K slices).
// EPI: 2 = bf16 relu(acc+bias) to outp ld N (FFN-up);
//      5 = split-K partial: slice z reads cols [z*K,(z+1)*K), writes BF16
//          partial to (bf16*)outp + z*M*N
template <int EPI>
__global__ __launch_bounds__(512, 1)
void gemm256(const bf16* __restrict__ A, const bf16* __restrict__ BT,
             const float* __restrict__ bias, void* __restrict__ outp,
             int M, int N, int K, int lda) {
  __shared__ alignas(16) short al[2][256 * 64];
  __shared__ alignas(16) short bl[2][256 * 64];
  const int t = threadIdx.x;
  const int gx = N >> 8;
  const int nwg = gridDim.x * gridDim.y;
  int id = blockIdx.y * gridDim.x + blockIdx.x;
  id = (id & 7) * (nwg >> 3) + (id >> 3);  // XCD-chunked (nwg%8==0)
  const int bx = id % gx, by = id / gx;
  const int m0 = by * 256, n0 = bx * 256;
  const int wid = t >> 6, l = t & 63, lr = l & 15, lk = l >> 4;
  const int wm = wid >> 2, wn = wid & 3;
  const int tr = t >> 3, tc = (t & 7) * 8;
  const int tcs = (((t & 7) ^ (tr & 7)) * 8);
  const int cro0 = ((lk ^ (lr & 7)) * 8);
  const int cro1 = (((4 + lk) ^ (lr & 7)) * 8);

  const bf16* Ab = (EPI == 5) ? A + (size_t)blockIdx.z * K : A;
  const bf16* BTb = (EPI == 5) ? BT + (size_t)blockIdx.z * K : BT;

  f32x4 acc[8][4];
#pragma unroll
  for (int i = 0; i < 8; ++i)
#pragma unroll
    for (int j = 0; j < 4; ++j) acc[i][j] = (f32x4)0.f;

#define STAGE2(buf, k0)                                                       \
  do {                                                                        \
    _Pragma("unroll") for (int it = 0; it < 4; ++it) {                        \
      const int row = it * 64 + tr;                                           \
      gload16(Ab + (size_t)(m0 + row) * lda + (k0) + tcs,                     \
              (char*)&al[buf][row * 64 + tc]);                                \
    }                                                                         \
    _Pragma("unroll") for (int it = 0; it < 4; ++it) {                        \
      const int row = it * 64 + tr;                                           \
      gload16(BTb + (size_t)(n0 + row) * lda + (k0) + tcs,                    \
              (char*)&bl[buf][row * 64 + tc]);                                \
    }                                                                         \
  } while (0)

#define COMPUTE2(cur)                                                         \
  do {                                                                        \
    _Pragma("unroll") for (int ks = 0; ks < 2; ++ks) {                        \
      const int cro = ks ? cro1 : cro0;                                       \
      short8 af[8], bfv[4];                                                   \
      _Pragma("unroll") for (int m = 0; m < 8; ++m) af[m] =                   \
          *reinterpret_cast<const short8*>(                                   \
              &al[cur][(wm * 128 + m * 16 + lr) * 64 + cro]);                 \
      _Pragma("unroll") for (int n = 0; n < 4; ++n) bfv[n] =                  \
          *reinterpret_cast<const short8*>(                                   \
              &bl[cur][(wn * 64 + n * 16 + lr) * 64 + cro]);                  \
      _Pragma("unroll") for (int m = 0; m < 8; ++m)                           \
          _Pragma("unroll") for (int n = 0; n < 4; ++n) acc[m][n] =           \
              __builtin_amdgcn_mfma_f32_16x16x32_bf16(af[m], bfv[n],          \
                                                      acc[m][n], 0, 0, 0);    \
    }                                                                         \
  } while (0)

  const int nt = K >> 6;
  STAGE2(0, 0);
  STAGE2(1, 64);
  for (int tk = 0; tk < nt; ++tk) {
    const int cur = tk & 1;
    if (tk < nt - 1)
      asm volatile("s_waitcnt vmcnt(8)" ::: "memory");
    else
      asm volatile("s_waitcnt vmcnt(0)" ::: "memory");
    __builtin_amdgcn_s_barrier();
    COMPUTE2(cur);
    if (tk + 2 < nt) {
      asm volatile("s_waitcnt lgkmcnt(0)" ::: "memory");
      __builtin_amdgcn_s_barrier();
      STAGE2(cur, (tk + 2) << 6);
    }
  }
#undef STAGE2
#undef COMPUTE2

  const int r0 = m0 + wm * 128, c0 = n0 + wn * 64;
  if constexpr (EPI == 2) {
#pragma unroll
    for (int m = 0; m < 8; ++m)
#pragma unroll
      for (int n = 0; n < 4; ++n) {
        const int col = c0 + n * 16 + lr;
        const float bcol = bias[col];
#pragma unroll
        for (int r = 0; r < 4; ++r) {
          const int row = r0 + m * 16 + lk * 4 + r;
          const float v = acc[m][n][r] + bcol;
          ((bf16*)outp)[(size_t)row * N + col] =
              __float2bfloat16(fmaxf(v, 0.f));
        }
      }
  } else {
    bf16* po = (bf16*)outp + (size_t)blockIdx.z * M * N;
#pragma unroll
    for (int m = 0; m < 8; ++m)
#pragma unroll
      for (int n = 0; n < 4; ++n) {
        const int col = c0 + n * 16 + lr;
#pragma unroll
        for (int r = 0; r < 4; ++r) {
          const int row = r0 + m * 16 + lk * 4 + r;
          po[(size_t)row * N + col] = __float2bfloat16(acc[m][n][r]);
        }
      }
  }
}

// ---- Merged QKV + cross-KV on the 256x256 structure (320 blocks) ----------
__global__ __launch_bounds__(512, 1)
void gemm256_dual(const bf16* __restrict__ A0, const bf16* __restrict__ BT0,
                  bf16* __restrict__ out0, bf16* __restrict__ vt0,
                  const bf16* __restrict__ A1, const bf16* __restrict__ BT1,
                  bf16* __restrict__ out1, bf16* __restrict__ vt1) {
  __shared__ alignas(16) short al[2][256 * 64];
  __shared__ alignas(16) short bl[2][256 * 64];
  const int t = threadIdx.x;
  const int raw = blockIdx.x;
  const int id = (raw & 7) * 40 + (raw >> 3);  // 320 = 8*40, bijective
  const bf16 *A, *BT;
  bf16 *outp, *vtp;
  int nv0, gx, pid;
  if (id < 192) {
    A = A0; BT = BT0; outp = out0; vtp = vt0; nv0 = 2048; gx = 12; pid = id;
  } else {
    A = A1; BT = BT1; outp = out1; vtp = vt1; nv0 = 1024; gx = 8;
    pid = id - 192;
  }
  const int K = 1024;
  const int bx = pid % gx, by = pid / gx;
  const int m0 = by * 256, n0 = bx * 256;
  const int wid = t >> 6, l = t & 63, lr = l & 15, lk = l >> 4;
  const int wm = wid >> 2, wn = wid & 3;
  const int tr = t >> 3, tc = (t & 7) * 8;
  const int tcs = (((t & 7) ^ (tr & 7)) * 8);
  const int cro0 = ((lk ^ (lr & 7)) * 8);
  const int cro1 = (((4 + lk) ^ (lr & 7)) * 8);

  f32x4 acc[8][4];
#pragma unroll
  for (int i = 0; i < 8; ++i)
#pragma unroll
    for (int j = 0; j < 4; ++j) acc[i][j] = (f32x4)0.f;

#define STAGE2(buf, k0)                                                       \
  do {                                                                        \
    _Pragma("unroll") for (int it = 0; it < 4; ++it) {                        \
      const int row = it * 64 + tr;                                           \
      gload16(A + (size_t)(m0 + row) * K + (k0) + tcs,                        \
              (char*)&al[buf][row * 64 + tc]);                                \
    }                                                                         \
    _Pragma("unroll") for (int it = 0; it < 4; ++it) {                        \
      const int row = it * 64 + tr;                                           \
      gload16(BT + (size_t)(n0 + row) * K + (k0) + tcs,                       \
              (char*)&bl[buf][row * 64 + tc]);                                \
    }                                                                         \
  } while (0)

#define COMPUTE2(cur)                                                         \
  do {                                                                        \
    _Pragma("unroll") for (int ks = 0; ks < 2; ++ks) {                        \
      const int cro = ks ? cro1 : cro0;                                       \
      short8 af[8], bfv[4];                                                   \
      _Pragma("unroll") for (int m = 0; m < 8; ++m) af[m] =                   \
          *reinterpret_cast<const short8*>(                                   \
              &al[cur][(wm * 128 + m * 16 + lr) * 64 + cro]);                 \
      _Pragma("unroll") for (int n = 0; n < 4; ++n) bfv[n] =                  \
          *reinterpret_cast<const short8*>(                                   \
              &bl[cur][(wn * 64 + n * 16 + lr) * 64 + cro]);                  \
      _Pragma("unroll") for (int m = 0; m < 8; ++m)                           \
          _Pragma("unroll") for (int n = 0; n < 4; ++n) acc[m][n] =           \
              __builtin_amdgcn_mfma_f32_16x16x32_bf16(af[m], bfv[n],          \
                                                      acc[m][n], 0, 0, 0);    \
    }                                                                         \
  } while (0)

  const int nt = K >> 6;
  STAGE2(0, 0);
  STAGE2(1, 64);
  for (int tk = 0; tk < nt; ++tk) {
    const int cur = tk & 1;
    if (tk < nt - 1)
      asm volatile("s_waitcnt vmcnt(8)" ::: "memory");
    else
      asm volatile("s_waitcnt vmcnt(0)" ::: "memory");
    __builtin_amdgcn_s_barrier();
    COMPUTE2(cur);
    if (tk + 2 < nt) {
      asm volatile("s_waitcnt lgkmcnt(0)" ::: "memory");
      __builtin_amdgcn_s_barrier();
      STAGE2(cur, (tk + 2) << 6);
    }
  }
#undef STAGE2
#undef COMPUTE2

  const int r0 = m0 + wm * 128, c0 = n0 + wn * 64;
#pragma unroll
  for (int m = 0; m < 8; ++m) {
    const int rowb = r0 + m * 16 + lk * 4;
    const int bb = rowb >> 10, s0 = rowb & 1023;
#pragma unroll
    for (int n = 0; n < 4; ++n) {
      const int col = c0 + n * 16 + lr;
      if (col < nv0) {
#pragma unroll
        for (int r = 0; r < 4; ++r)
          outp[(size_t)(rowb + r) * nv0 + col] =
              __float2bfloat16(acc[m][n][r]);
      } else {
        ushort4 u;
        u.x = (unsigned short)f2bf(acc[m][n][0]);
        u.y = (unsigned short)f2bf(acc[m][n][1]);
        u.z = (unsigned short)f2bf(acc[m][n][2]);
        u.w = (unsigned short)f2bf(acc[m][n][3]);
        const size_t vidx = ((size_t)bb * 1024 + (col - nv0)) * 1024 + s0;
        *reinterpret_cast<ushort4*>(vtp + vidx) = u;
      }
    }
  }
}

// ---------------- Flash attention v8: LDS-staged K/V, 3-stage pipeline ------
template <bool CAUSAL>
__global__ __launch_bounds__(256, 2)
void flash8(const bf16* __restrict__ Qb, int ldq,
            const bf16* __restrict__ Kb, int ldk,
            const bf16* __restrict__ VTb, bf16* __restrict__ Ob) {
  __shared__ alignas(16) short kl[3][64 * 64];
  __shared__ alignas(16) short vl[3][64 * 64];
  __shared__ alignas(16) short pl[4][32 * 72];
  const int t = threadIdx.x, wv = t >> 6, l = t & 63, lr = l & 15, lk = l >> 4;
  const int raw = blockIdx.y * 8 + blockIdx.x;
  const int id = (raw & 7) * 64 + (raw >> 3);
  const int qb = id & 7, bh = id >> 3;
  const int b = bh >> 4, h = bh & 15;
  const size_t rowbase = (size_t)b * 1024;
  const int q0 = qb * 128 + wv * 32;
  const bf16* Vbase = VTb + (rowbase + h * 64) * 1024;

  const int tr = t >> 3;
  const int tcd = (t & 7) * 8;
  const int tcs = (((t & 7) ^ (tr & 7)) * 8);
  const int cro0 = ((lk ^ (lr & 7)) * 8);
  const int cro1 = (((4 + lk) ^ (lr & 7)) * 8);

  short8 qf[2][2];
#pragma unroll
  for (int m = 0; m < 2; ++m)
#pragma unroll
    for (int ks = 0; ks < 2; ++ks)
      qf[m][ks] = *reinterpret_cast<const short8*>(
          Qb + (rowbase + q0 + m * 16 + lr) * ldq + h * 64 + ks * 32 + lk * 8);

  short8 ones;
#pragma unroll
  for (int j = 0; j < 8; ++j) ones[j] = (short)0x3F80;  // bf16 1.0

  f32x4 accO[2][4];
  f32x4 accL[2];
#pragma unroll
  for (int m = 0; m < 2; ++m) {
#pragma unroll
    for (int n = 0; n < 4; ++n) accO[m][n] = (f32x4)0.f;
    accL[m] = (f32x4)0.f;
  }

  const int ntb = CAUSAL ? (qb * 2 + 2) : 16;
  const int myLast = q0 >> 6;

#define FSTAGE(buf, kv0)                                                      \
  do {                                                                        \
    _Pragma("unroll") for (int it = 0; it < 2; ++it) {                        \
      const int row = it * 32 + tr;                                           \
      gload16(Kb + (rowbase + (kv0) + row) * ldk + h * 64 + tcs,              \
              (char*)&kl[buf][row * 64 + tcd]);                               \
    }                                                                         \
    _Pragma("unroll") for (int it = 0; it < 2; ++it) {                        \
      const int row = it * 32 + tr;                                           \
      gload16(Vbase + (size_t)row * 1024 + (kv0) + tcs,                       \
              (char*)&vl[buf][row * 64 + tcd]);                               \
    }                                                                         \
  } while (0)

  FSTAGE(0, 0);
  FSTAGE(1, 64);
  int cur = 0;
  for (int tk = 0; tk < ntb; ++tk) {
    if (tk < ntb - 1)
      asm volatile("s_waitcnt vmcnt(4)" ::: "memory");
    else
      asm volatile("s_waitcnt vmcnt(0)" ::: "memory");
    __builtin_amdgcn_s_barrier();
    if (tk + 2 < ntb) {
      int stg = cur + 2;
      if (stg >= 3) stg -= 3;
      FSTAGE(stg, (tk + 2) << 6);
    }
    if (!CAUSAL || tk <= myLast) {
      const int kv0 = tk * 64;
      const bool needmask = CAUSAL && (tk == myLast);
      f32x4 sa[2][4];
#pragma unroll
      for (int m = 0; m < 2; ++m)
#pragma unroll
        for (int n = 0; n < 4; ++n) sa[m][n] = (f32x4)0.f;
#pragma unroll
      for (int ks = 0; ks < 2; ++ks) {
        const int cro = ks ? cro1 : cro0;
        short8 kf[4];
#pragma unroll
        for (int n = 0; n < 4; ++n)
          kf[n] = *reinterpret_cast<const short8*>(
              &kl[cur][(n * 16 + lr) * 64 + cro]);
        __builtin_amdgcn_s_setprio(1);
#pragma unroll
        for (int m = 0; m < 2; ++m)
#pragma unroll
          for (int n = 0; n < 4; ++n)
            sa[m][n] = __builtin_amdgcn_mfma_f32_16x16x32_bf16(
                qf[m][ks], kf[n], sa[m][n], 0, 0, 0);
        __builtin_amdgcn_s_setprio(0);
      }
#pragma unroll
      for (int m = 0; m < 2; ++m) {
#pragma unroll
        for (int r = 0; r < 4; ++r) {
          const int row = q0 + m * 16 + lk * 4 + r;
          float s0 = sa[m][0][r] * 0.125f, s1 = sa[m][1][r] * 0.125f;
          float s2 = sa[m][2][r] * 0.125f, s3 = sa[m][3][r] * 0.125f;
          if (needmask) {
            if (kv0 + 0 + lr > row) s0 = -1e30f;
            if (kv0 + 16 + lr > row) s1 = -1e30f;
            if (kv0 + 32 + lr > row) s2 = -1e30f;
            if (kv0 + 48 + lr > row) s3 = -1e30f;
          }
          const float p0 = __expf(s0), p1 = __expf(s1);
          const float p2 = __expf(s2), p3 = __expf(s3);
          const int prow = m * 16 + lk * 4 + r;
          pl[wv][prow * 72 + lr + 0] = f2bf(p0);
          pl[wv][prow * 72 + lr + 16] = f2bf(p1);
          pl[wv][prow * 72 + lr + 32] = f2bf(p2);
          pl[wv][prow * 72 + lr + 48] = f2bf(p3);
        }
      }
#pragma unroll
      for (int ks = 0; ks < 2; ++ks) {
        const int cro = ks ? cro1 : cro0;
        short8 pf[2], vf[4];
#pragma unroll
        for (int m = 0; m < 2; ++m)
          pf[m] = *reinterpret_cast<const short8*>(
              &pl[wv][(m * 16 + lr) * 72 + ks * 32 + lk * 8]);
#pragma unroll
        for (int n = 0; n < 4; ++n)
          vf[n] = *reinterpret_cast<const short8*>(
              &vl[cur][(n * 16 + lr) * 64 + cro]);
        __builtin_amdgcn_s_setprio(1);
#pragma unroll
        for (int m = 0; m < 2; ++m) {
#pragma unroll
          for (int n = 0; n < 4; ++n)
            accO[m][n] = __builtin_amdgcn_mfma_f32_16x16x32_bf16(
                pf[m], vf[n], accO[m][n], 0, 0, 0);
          accL[m] = __builtin_amdgcn_mfma_f32_16x16x32_bf16(
              pf[m], ones, accL[m], 0, 0, 0);
        }
        __builtin_amdgcn_s_setprio(0);
      }
    }
    cur = (cur + 1 == 3) ? 0 : cur + 1;
  }
#undef FSTAGE

#pragma unroll
  for (int m = 0; m < 2; ++m)
#pragma unroll
    for (int n = 0; n < 4; ++n)
#pragma unroll
      for (int r = 0; r < 4; ++r) {
        const int row = q0 + m * 16 + lk * 4 + r;
        const int col = n * 16 + lr;
        const float o = accO[m][n][r] / accL[m][r];
        Ob[(rowbase + row) * 1024 + h * 64 + col] = __float2bfloat16(o);
      }
}

// ---------------- launch ----------------
extern "C" void kernel_launch(void* const* d_in, const int* in_sizes, int n_in,
                              void* d_out, int out_size, void* d_ws,
                              size_t ws_size, hipStream_t stream) {
  const float* x = (const float*)d_in[0];
  const float* kv_in = (const float*)d_in[1];
  const float* sa_wq = (const float*)d_in[4];
  const float* sa_wk = (const float*)d_in[5];
  const float* sa_wv = (const float*)d_in[6];
  const float* sa_wo = (const float*)d_in[7];
  const float* ca_wq = (const float*)d_in[8];
  const float* ca_wk = (const float*)d_in[9];
  const float* ca_wv = (const float*)d_in[10];
  const float* ca_wo = (const float*)d_in[11];
  const float* fc_w1 = (const float*)d_in[12];
  const float* fc_b1 = (const float*)d_in[13];
  const float* fc_w2 = (const float*)d_in[14];
  const float* fc_b2 = (const float*)d_in[15];
  const float* ln1_g = (const float*)d_in[16];
  const float* ln1_b = (const float*)d_in[17];
  const float* ln2_g = (const float*)d_in[18];
  const float* ln2_b = (const float*)d_in[19];
  const float* ln3_g = (const float*)d_in[20];
  const float* ln3_b = (const float*)d_in[21];

  char* ws = (char*)d_ws;
  const size_t MB = 1024 * 1024;
  bf16* W = (bf16*)ws;                    // 16M elems = 32 MB
  bf16* w1T = W + 8 * MB;
  bf16* w2T = W + 12 * MB;
  float* z = (float*)(ws + 32 * MB);      // 16 MB
  bf16* t0 = (bf16*)(ws + 48 * MB);       // 8 MB
  bf16* qkvb = (bf16*)(ws + 56 * MB);     // [4096][2048] Q|K, 16 MB
  bf16* vts = (bf16*)(ws + 72 * MB);      // self V^T [4096][1024], 8 MB
  bf16* kb = (bf16*)(ws + 80 * MB);       // cross K [4096][1024], 8 MB
  bf16* vtc = (bf16*)(ws + 88 * MB);      // cross V^T [4096][1024], 8 MB
  bf16* qb = (bf16*)(ws + 96 * MB);       // 8 MB
  bf16* ctx = (bf16*)(ws + 104 * MB);     // 8 MB
  bf16* kvln = (bf16*)(ws + 112 * MB);    // 8 MB
  bf16* hb = (bf16*)(ws + 120 * MB);      // [4096][4096] 32 MB
  // FFN-down bf16 split-K partials: 4 x 8 MB over the dead attention region
  bf16* partsb = (bf16*)(ws + 56 * MB);   // 32 MB (qkvb..vtc dead by then)
  const size_t PSL = (size_t)4096 * 1024;

  const dim3 B256(256);
  wtr8<<<dim3(32, 32, 8), B256, 0, stream>>>(sa_wq, sa_wk, sa_wv, sa_wo,
                                             ca_wq, ca_wk, ca_wv, ca_wo, W);
  // merged fc_w1 + fc_w2 transpose (z = 2)
  wtr2<<<dim3(4096, 1, 2), B256, 0, stream>>>(fc_w1, w1T, fc_w2, w2T);

  // merged LN1(x) + LN2(kv) (independent inputs, 8192 rows)
  ln_k2<<<8192, B256, 0, stream>>>(x, ln1_g, ln1_b, t0,
                                   kv_in, ln2_g, ln2_b, kvln);
  // merged self-QKV + cross-KV: 320 blocks on the 256x256 structure
  gemm256_dual<<<dim3(320), dim3(512), 0, stream>>>(
      t0, W, qkvb, vts, kvln, W + 5 * MB, kb, vtc);

  // ---- self attention ----
  flash8<true><<<dim3(8, 64), B256, 0, stream>>>(
      qkvb, 2048, qkvb + 1024, 2048, vts, ctx);
  gemm_bt<64, 1><<<dim3(8, 64), B256, 0, stream>>>(
      ctx, W + 3 * MB, nullptr, x, z, 4096, 1024, 1024, nullptr, 0);

  // ---- cross attention ----
  ln_k<<<4096, B256, 0, stream>>>(z, ln2_g, ln2_b, t0);
  gemm_bt<64, 0><<<dim3(8, 64), B256, 0, stream>>>(
      t0, W + 4 * MB, nullptr, nullptr, qb, 4096, 1024, 1024, nullptr, 0);
  flash8<false><<<dim3(8, 64), B256, 0, stream>>>(
      qb, 1024, kb, 1024, vtc, ctx);
  gemm_bt<64, 1><<<dim3(8, 64), B256, 0, stream>>>(
      ctx, W + 7 * MB, nullptr, z, z, 4096, 1024, 1024, nullptr, 0);

  // ---- FFN ----
  ln_k<<<4096, B256, 0, stream>>>(z, ln3_g, ln3_b, t0);
  gemm256<2><<<dim3(16, 16), dim3(512), 0, stream>>>(
      t0, w1T, fc_b1, hb, 4096, 4096, 1024, 1024);
  // FFN-down split-K x4 on the 256x256 structure, BF16 partials
  gemm256<5><<<dim3(4, 16, 4), dim3(512), 0, stream>>>(
      hb, w2T, nullptr, partsb, 4096, 1024, 1024, 4096);
  ffn_add4b<<<4096, B256, 0, stream>>>(
      (const ushort4*)(partsb + 0 * PSL), (const ushort4*)(partsb + 1 * PSL),
      (const ushort4*)(partsb + 2 * PSL), (const ushort4*)(partsb + 3 * PSL),
      (const float4*)z, (const float4*)fc_b2, (float4*)d_out);
}